// Round 3
// baseline (337.469 us; speedup 1.0000x reference)
//
#include <hip/hip_runtime.h>
#include <math.h>

#define NNODES   50000
#define NFEAT    512
#define NCLASS   256
#define NEG_SLOPE 0.2f
#define GBLK     782     // 782 * 64 rows
#define BCAP     64      // per-row bucket capacity; P(deg>64) ~ 1e-18/row

typedef __attribute__((ext_vector_type(8))) short short8;
typedef __attribute__((ext_vector_type(4))) float floatx4;

__device__ __forceinline__ unsigned short f2bf(float f) {
    unsigned u = __builtin_bit_cast(unsigned, f);
    u += 0x7fffu + ((u >> 16) & 1u);          // RNE
    return (unsigned short)(u >> 16);
}
__device__ __forceinline__ float bf2f_lo(unsigned u) {
    return __builtin_bit_cast(float, u << 16);
}
__device__ __forceinline__ float bf2f_hi(unsigned u) {
    return __builtin_bit_cast(float, u & 0xffff0000u);
}
// pack two floats -> (bf16(lo) | bf16(hi)<<16), round-half-away
__device__ __forceinline__ unsigned pack_bf16_rh(float lo, float hi) {
    const unsigned ulo = __builtin_bit_cast(unsigned, lo) + 0x8000u;
    const unsigned uhi = __builtin_bit_cast(unsigned, hi) + 0x8000u;
    return __builtin_amdgcn_perm(uhi, ulo, 0x07060302);
}

#if __has_builtin(__builtin_amdgcn_fdot2_f32_bf16)
#define HAVE_DOT2 1
typedef __attribute__((ext_vector_type(2))) __bf16 bfx2;
__device__ __forceinline__ float dot2bf(unsigned hpair, unsigned epair, float acc) {
    return __builtin_amdgcn_fdot2_f32_bf16(__builtin_bit_cast(bfx2, hpair),
                                           __builtin_bit_cast(bfx2, epair), acc, false);
}
#endif

// ---------------------------------------------------------------------------
// Init: W [512][256] fp32 -> Wt [256][512] bf16 transposed; zero cursor.
// ---------------------------------------------------------------------------
__global__ __launch_bounds__(256) void init_kernel(const float* __restrict__ W,
                                                   unsigned short* __restrict__ Wt,
                                                   int* __restrict__ cursor, int zn) {
    const int i = blockIdx.x * 256 + threadIdx.x;     // 0..131071
    const int n = i >> 9;
    const int k = i & 511;
    Wt[i] = f2bf(W[(size_t)k * NCLASS + n]);
    if (i < zn) cursor[i] = 0;
}

// ---------------------------------------------------------------------------
// MFMA GEMM: 64x256 tile, 782 blocks, 4 waves as 2x2 (wm: 32-row half,
// wn: 128-col half), acc 2x8.
// K-loop = depth-2 counted-vmcnt pipeline (T3+T4): triple-buffered LDS,
// ALL staging via global_load_lds (A staged as fp32, converted to bf16
// in-register after ds_read) so the loop has zero compiler-tracked VMEM
// loads and the literal vmcnt(6) counts are exact. One raw s_barrier per
// K-step; vmcnt never drained to 0 in steady state.
// LDS layouts XOR-chunk-swizzled via pre-swizzled GLOBAL source addresses
// (linear DMA dest) + matching XOR on the ds_read side:
//   A [64][8 chunks of 16B]: phys_chunk = log_chunk ^ (row&7)   -> 2-way (free)
//   B [256][4 chunks of 16B]: phys_chunk = log_chunk ^ ((row>>1)&3) -> 2-way
// ---------------------------------------------------------------------------
__global__ __launch_bounds__(256, 2) void gemm_mfma_kernel(const float* __restrict__ x,
                                                           const unsigned short* __restrict__ Wt,
                                                           unsigned short* __restrict__ hb,
                                                           const float* __restrict__ a,
                                                           float* __restrict__ s_row,
                                                           float* __restrict__ s_col,
                                                           int M) {
    __shared__ union {
        struct { float As[3][64 * 32]; short Bs[3][256 * 32]; } k;  // 24KB + 48KB = 72KB
        short Cs[32 * 260];                                         // 16.6KB (epilogue)
    } u;

    const int tid  = threadIdx.x;
    const int w    = tid >> 6;
    const int lane = tid & 63;
    const int rowbase = blockIdx.x * 64;

    const int wm = w & 1;     // 32-row half
    const int wn = w >> 1;    // 128-col half
    const int fm = lane & 15;
    const int fq = lane >> 4;

    floatx4 acc[2][8];
#pragma unroll
    for (int i = 0; i < 2; ++i)
#pragma unroll
        for (int j = 0; j < 8; ++j)
            acc[i][j] = (floatx4){0.f, 0.f, 0.f, 0.f};

    // ---- staging source addresses (pre-swizzled per lane) ----
    // A: wave w stages regions t=0,1: rows (w*2+t)*8 + (lane>>3); 8 rows x 128B.
    const int arloc = lane >> 3;              // 0..7
    const int alch  = (lane & 7) ^ arloc;     // logical chunk fetched for phys slot lane&7
    const int ar0 = min(rowbase + (w * 2 + 0) * 8 + arloc, M - 1);
    const int ar1 = min(rowbase + (w * 2 + 1) * 8 + arloc, M - 1);
    const float* asrc0 = x + (size_t)ar0 * NFEAT + alch * 4;
    const float* asrc1 = x + (size_t)ar1 * NFEAT + alch * 4;
    // B: wave w stages segs 4w+t, t=0..3: rows seg*16 + (lane>>2); 16 rows x 64B.
    const int brloc = lane >> 2;              // 0..15
    const int blch  = (lane & 3) ^ ((lane >> 3) & 3);
    const unsigned short* bsrc[4];
#pragma unroll
    for (int t = 0; t < 4; ++t) {
        const int seg = w * 4 + t;
        bsrc[t] = Wt + (size_t)(seg * 16 + brloc) * NFEAT + blch * 8;
    }

#define STAGE_TILE(buf, k0)                                                                   \
    {                                                                                         \
        __builtin_amdgcn_global_load_lds(                                                     \
            (const __attribute__((address_space(1))) void*)(asrc0 + (k0)),                    \
            (__attribute__((address_space(3))) void*)(&u.k.As[buf][(w * 2 + 0) * 8 * 32]),    \
            16, 0, 0);                                                                        \
        __builtin_amdgcn_global_load_lds(                                                     \
            (const __attribute__((address_space(1))) void*)(asrc1 + (k0)),                    \
            (__attribute__((address_space(3))) void*)(&u.k.As[buf][(w * 2 + 1) * 8 * 32]),    \
            16, 0, 0);                                                                        \
        _Pragma("unroll")                                                                     \
        for (int t = 0; t < 4; ++t) {                                                         \
            __builtin_amdgcn_global_load_lds(                                                 \
                (const __attribute__((address_space(1))) void*)(bsrc[t] + (k0)),              \
                (__attribute__((address_space(3))) void*)(&u.k.Bs[buf][(w * 4 + t) * 512]),   \
                16, 0, 0);                                                                    \
        }                                                                                     \
    }

    // ---- prologue: stage tiles 0 and 1 ----
    STAGE_TILE(0, 0)
    STAGE_TILE(1, 32)
    asm volatile("s_waitcnt vmcnt(6)" ::: "memory");   // tile 0 done; tile 1 in flight
    __builtin_amdgcn_sched_barrier(0);
    __builtin_amdgcn_s_barrier();
    __builtin_amdgcn_sched_barrier(0);

    const int keyB = (fm >> 1) & 3;
    const int r7   = fm & 7;

#pragma unroll
    for (int k = 0; k < 16; ++k) {
        const int cur = k % 3;
        if (k < 14) {
            const int nb = (k + 2) % 3;
            STAGE_TILE(nb, (k + 2) * 32)
        }

        // A fragments: 2 x ds_read_b128 (fp32) + in-register bf16 pack.
        short8 af[2];
#pragma unroll
        for (int mt = 0; mt < 2; ++mt) {
            const int row = wm * 32 + mt * 16 + fm;
            const int p0 = (2 * fq) ^ r7;
            const int p1 = (2 * fq + 1) ^ r7;
            const float4 a0 = *(const float4*)&u.k.As[cur][row * 32 + p0 * 4];
            const float4 a1 = *(const float4*)&u.k.As[cur][row * 32 + p1 * 4];
            uint4 o;
            o.x = pack_bf16_rh(a0.x, a0.y);
            o.y = pack_bf16_rh(a0.z, a0.w);
            o.z = pack_bf16_rh(a1.x, a1.y);
            o.w = pack_bf16_rh(a1.z, a1.w);
            af[mt] = __builtin_bit_cast(short8, o);
        }
#pragma unroll
        for (int nt = 0; nt < 8; ++nt) {
            const int row = wn * 128 + nt * 16 + fm;
            const int pb = fq ^ keyB;
            const short8 bfr = *(const short8*)&u.k.Bs[cur][row * 32 + pb * 8];
            acc[0][nt] = __builtin_amdgcn_mfma_f32_16x16x32_bf16(af[0], bfr, acc[0][nt], 0, 0, 0);
            acc[1][nt] = __builtin_amdgcn_mfma_f32_16x16x32_bf16(af[1], bfr, acc[1][nt], 0, 0, 0);
        }

        if (k < 15) {
            if (k < 14) {
                asm volatile("s_waitcnt vmcnt(6)" ::: "memory");   // tile k+1 done; k+2 in flight
            } else {
                asm volatile("s_waitcnt vmcnt(0)" ::: "memory");   // last staged tile (15) done
            }
            __builtin_amdgcn_sched_barrier(0);
            __builtin_amdgcn_s_barrier();
            __builtin_amdgcn_sched_barrier(0);
        }
    }

    // Epilogue: 2 passes of 32 rows through Cs (stride 260).
#pragma unroll
    for (int p = 0; p < 2; ++p) {
        __syncthreads();
        if (wm == p) {
#pragma unroll
            for (int mt = 0; mt < 2; ++mt)
#pragma unroll
                for (int nt = 0; nt < 8; ++nt)
#pragma unroll
                    for (int r = 0; r < 4; ++r)
                        u.Cs[(mt * 16 + fq * 4 + r) * 260 + wn * 128 + nt * 16 + fm] =
                            (short)f2bf(acc[mt][nt][r]);
        }
        __syncthreads();
        // 32 rows x 256 cols: one wave handles one row/iter
#pragma unroll
        for (int kk = 0; kk < 8; ++kk) {
            const int idx = tid + kk * 256;
            const int lrow = idx >> 6;
            const int c4 = (idx & 63) << 2;
            const int grow = rowbase + p * 32 + lrow;
            const uint2 vv = *(const uint2*)&u.Cs[lrow * 260 + c4];
            const float f0 = bf2f_lo(vv.x), f1 = bf2f_hi(vv.x);
            const float f2 = bf2f_lo(vv.y), f3 = bf2f_hi(vv.y);
            const float4 A1 = *(const float4*)&a[c4];
            const float4 A2 = *(const float4*)&a[NCLASS + c4];
            float p1 = f0 * A1.x + f1 * A1.y + f2 * A1.z + f3 * A1.w;
            float p2 = f0 * A2.x + f1 * A2.y + f2 * A2.z + f3 * A2.w;
#pragma unroll
            for (int off = 1; off < 64; off <<= 1) {
                p1 += __shfl_xor(p1, off);
                p2 += __shfl_xor(p2, off);
            }
            if (grow < M) {
                *(uint2*)&hb[(size_t)grow * NCLASS + c4] = vv;
                if (lane == 0) {
                    s_row[grow] = p1;
                    s_col[grow] = p2;
                }
            }
        }
    }
}

// ---------------------------------------------------------------------------
// Scatter (slim): group edges into fixed-capacity per-row buckets, col only.
// ---------------------------------------------------------------------------
__global__ __launch_bounds__(256) void scatter_kernel(const int* __restrict__ row,
                                                      const int* __restrict__ col,
                                                      int* __restrict__ cursor,
                                                      int* __restrict__ bucket, int e) {
    const int i = blockIdx.x * 256 + threadIdx.x;
    if (i >= e) return;
    const int r = row[i];
    const int c = col[i];
    const int pos = atomicAdd(&cursor[r], 1);
    if (pos < BCAP) bucket[((size_t)r << 6) + pos] = c;
}

// ---------------------------------------------------------------------------
// Aggregation + elu + log_softmax. One wave per row; lane holds 4 features.
// e = exp(-lrelu(s_row[r] + s_col[c])) computed inline (uniform broadcasts).
// ---------------------------------------------------------------------------
__global__ __launch_bounds__(256) void aggregate_kernel(const unsigned short* __restrict__ hb,
                                                        const int* __restrict__ bucket,
                                                        const int* __restrict__ cnt,
                                                        const float* __restrict__ s_row,
                                                        const float* __restrict__ s_col,
                                                        float* __restrict__ out, int n) {
    const int wave = (int)((blockIdx.x * (size_t)blockDim.x + threadIdx.x) >> 6);
    const int lane = threadIdx.x & 63;
    if (wave >= n) return;
    const int r = wave;
    const int jb = r << 6;
    const int je = jb + min(cnt[r], BCAP);
    const int fo = lane << 2;
    const float sr = s_row[r];

    float rowsum = 0.f;
    int j = jb;

#define EDGE_E(c) ({ const float _l = sr + s_col[c];                         \
                     const float _lr = _l > 0.f ? _l : NEG_SLOPE * _l;       \
                     __expf(-_lr); })

#ifdef HAVE_DOT2
    float ac0 = 0.f, ac1 = 0.f, ac2 = 0.f, ac3 = 0.f;
    for (; j + 3 < je; j += 4) {
        const int4 cv = *(const int4*)&bucket[j];
        const uint2 g0 = *(const uint2*)&hb[(size_t)cv.x * NCLASS + fo];
        const uint2 g1 = *(const uint2*)&hb[(size_t)cv.y * NCLASS + fo];
        const uint2 g2 = *(const uint2*)&hb[(size_t)cv.z * NCLASS + fo];
        const uint2 g3 = *(const uint2*)&hb[(size_t)cv.w * NCLASS + fo];
        const float e0 = EDGE_E(cv.x);
        const float e1 = EDGE_E(cv.y);
        const float e2 = EDGE_E(cv.z);
        const float e3 = EDGE_E(cv.w);
        const unsigned ep01 = pack_bf16_rh(e0, e1);
        const unsigned ep23 = pack_bf16_rh(e2, e3);
        rowsum += (e0 + e1) + (e2 + e3);
        ac0 = dot2bf(__builtin_amdgcn_perm(g1.x, g0.x, 0x05040100), ep01, ac0);
        ac1 = dot2bf(__builtin_amdgcn_perm(g1.x, g0.x, 0x07060302), ep01, ac1);
        ac2 = dot2bf(__builtin_amdgcn_perm(g1.y, g0.y, 0x05040100), ep01, ac2);
        ac3 = dot2bf(__builtin_amdgcn_perm(g1.y, g0.y, 0x07060302), ep01, ac3);
        ac0 = dot2bf(__builtin_amdgcn_perm(g3.x, g2.x, 0x05040100), ep23, ac0);
        ac1 = dot2bf(__builtin_amdgcn_perm(g3.x, g2.x, 0x07060302), ep23, ac1);
        ac2 = dot2bf(__builtin_amdgcn_perm(g3.y, g2.y, 0x05040100), ep23, ac2);
        ac3 = dot2bf(__builtin_amdgcn_perm(g3.y, g2.y, 0x07060302), ep23, ac3);
    }
    float4 acc = make_float4(ac0, ac1, ac2, ac3);
#else
    float4 acc = make_float4(0.f, 0.f, 0.f, 0.f);
    for (; j + 3 < je; j += 4) {
        const int4 cv = *(const int4*)&bucket[j];
        const uint2 g0 = *(const uint2*)&hb[(size_t)cv.x * NCLASS + fo];
        const uint2 g1 = *(const uint2*)&hb[(size_t)cv.y * NCLASS + fo];
        const uint2 g2 = *(const uint2*)&hb[(size_t)cv.z * NCLASS + fo];
        const uint2 g3 = *(const uint2*)&hb[(size_t)cv.w * NCLASS + fo];
        const float e0 = EDGE_E(cv.x);
        const float e1 = EDGE_E(cv.y);
        const float e2 = EDGE_E(cv.z);
        const float e3 = EDGE_E(cv.w);
        rowsum += (e0 + e1) + (e2 + e3);
        acc.x += e0 * bf2f_lo(g0.x) + e1 * bf2f_lo(g1.x) + e2 * bf2f_lo(g2.x) + e3 * bf2f_lo(g3.x);
        acc.y += e0 * bf2f_hi(g0.x) + e1 * bf2f_hi(g1.x) + e2 * bf2f_hi(g2.x) + e3 * bf2f_hi(g3.x);
        acc.z += e0 * bf2f_lo(g0.y) + e1 * bf2f_lo(g1.y) + e2 * bf2f_lo(g2.y) + e3 * bf2f_lo(g3.y);
        acc.w += e0 * bf2f_hi(g0.y) + e1 * bf2f_hi(g1.y) + e2 * bf2f_hi(g2.y) + e3 * bf2f_hi(g3.y);
    }
#endif
    for (; j < je; ++j) {
        const int c = bucket[j];
        const uint2 g = *(const uint2*)&hb[(size_t)c * NCLASS + fo];
        const float e = EDGE_E(c);
        rowsum += e;
        acc.x += e * bf2f_lo(g.x);
        acc.y += e * bf2f_hi(g.x);
        acc.z += e * bf2f_lo(g.y);
        acc.w += e * bf2f_hi(g.y);
    }

    const float inv = 1.f / rowsum;
    float v[4] = {acc.x * inv, acc.y * inv, acc.z * inv, acc.w * inv};
#pragma unroll
    for (int i = 0; i < 4; ++i)
        v[i] = v[i] > 0.f ? v[i] : __expf(v[i]) - 1.f;

    float m = fmaxf(fmaxf(v[0], v[1]), fmaxf(v[2], v[3]));
#pragma unroll
    for (int off = 32; off > 0; off >>= 1) m = fmaxf(m, __shfl_xor(m, off));
    float s = 0.f;
#pragma unroll
    for (int i = 0; i < 4; ++i) s += __expf(v[i] - m);
#pragma unroll
    for (int off = 32; off > 0; off >>= 1) s += __shfl_xor(s, off);
    const float lse = m + __logf(s);

    float4 o = make_float4(v[0] - lse, v[1] - lse, v[2] - lse, v[3] - lse);
    *(float4*)&out[(size_t)r * NCLASS + fo] = o;
}

// ---------------------------------------------------------------------------
extern "C" void kernel_launch(void* const* d_in, const int* in_sizes, int n_in,
                              void* d_out, int out_size, void* d_ws, size_t ws_size,
                              hipStream_t stream) {
    const float* x  = (const float*)d_in[0];
    const float* W  = (const float*)d_in[1];
    const float* a  = (const float*)d_in[2];
    const int* edge = (const int*)d_in[3];
    float* out = (float*)d_out;

    const int M = in_sizes[0] / NFEAT;         // 50000
    const int E = in_sizes[3] / 2;             // 850000
    const int* row = edge;
    const int* col = edge + E;

    char* ws = (char*)d_ws;
    size_t off = 0;
    auto carve = [&](size_t bytes) -> char* {
        char* p = ws + off;
        off = (off + bytes + 255) & ~(size_t)255;
        return p;
    };
    unsigned short* Wt = (unsigned short*)carve((size_t)NCLASS * NFEAT * sizeof(short));
    unsigned short* hb = (unsigned short*)carve((size_t)M * NCLASS * sizeof(short)); // 25.6MB
    int*   cursor   = (int*)carve((size_t)M * sizeof(int));
    float* s_row    = (float*)carve((size_t)M * sizeof(float));
    float* s_col    = (float*)carve((size_t)M * sizeof(float));
    int*   bucket   = (int*)carve((size_t)M * BCAP * sizeof(int));   // 12.8MB

    init_kernel<<<512, 256, 0, stream>>>(W, Wt, cursor, M);

    gemm_mfma_kernel<<<GBLK, 256, 0, stream>>>(x, Wt, hb, a, s_row, s_col, M);

    scatter_kernel<<<(E + 255) / 256, 256, 0, stream>>>(row, col, cursor, bucket, E);

    aggregate_kernel<<<(M + 3) / 4, 256, 0, stream>>>(hb, bucket, cursor, s_row, s_col, out, M);
}

// Round 5
// 314.866 us; speedup vs baseline: 1.0718x; 1.0718x over previous
//
#include <hip/hip_runtime.h>
#include <math.h>

#define NNODES   50000
#define NFEAT    512
#define NCLASS   256
#define NEG_SLOPE 0.2f
#define GBLK     782     // 782 * 64 rows
#define BCAP     64      // per-row bucket capacity; P(deg>64) ~ 1e-18/row

typedef __attribute__((ext_vector_type(8))) short short8;
typedef __attribute__((ext_vector_type(4))) float floatx4;

__device__ __forceinline__ unsigned short f2bf(float f) {
    unsigned u = __builtin_bit_cast(unsigned, f);
    u += 0x7fffu + ((u >> 16) & 1u);          // RNE
    return (unsigned short)(u >> 16);
}
__device__ __forceinline__ float bf2f_lo(unsigned u) {
    return __builtin_bit_cast(float, u << 16);
}
__device__ __forceinline__ float bf2f_hi(unsigned u) {
    return __builtin_bit_cast(float, u & 0xffff0000u);
}
// pack two floats -> (bf16(lo) | bf16(hi)<<16), round-half-away
__device__ __forceinline__ unsigned pack_bf16_rh(float lo, float hi) {
    const unsigned ulo = __builtin_bit_cast(unsigned, lo) + 0x8000u;
    const unsigned uhi = __builtin_bit_cast(unsigned, hi) + 0x8000u;
    return __builtin_amdgcn_perm(uhi, ulo, 0x07060302);
}

#if __has_builtin(__builtin_amdgcn_fdot2_f32_bf16)
#define HAVE_DOT2 1
typedef __attribute__((ext_vector_type(2))) __bf16 bfx2;
__device__ __forceinline__ float dot2bf(unsigned hpair, unsigned epair, float acc) {
    return __builtin_amdgcn_fdot2_f32_bf16(__builtin_bit_cast(bfx2, hpair),
                                           __builtin_bit_cast(bfx2, epair), acc, false);
}
#endif

// ---------------------------------------------------------------------------
// Init: W [512][256] fp32 -> Wt [256][512] bf16 transposed; zero cursor.
// ---------------------------------------------------------------------------
__global__ __launch_bounds__(256) void init_kernel(const float* __restrict__ W,
                                                   unsigned short* __restrict__ Wt,
                                                   int* __restrict__ cursor, int zn) {
    const int i = blockIdx.x * 256 + threadIdx.x;     // 0..131071
    const int n = i >> 9;
    const int k = i & 511;
    Wt[i] = f2bf(W[(size_t)k * NCLASS + n]);
    if (i < zn) cursor[i] = 0;
}

// ---------------------------------------------------------------------------
// MFMA GEMM (VERIFIED R2 structure, unchanged): 64x256 tile, 782 blocks,
// 4 waves as 2x2 (wm: 32-row half, wn: 128-col half), acc 2x8.
// Double-buffered LDS, 2-phase pipeline: issue next tile's loads (A fp32->
// regs, B global_load_lds) BEFORE the ds_read+MFMA of the current buffer;
// pack+ds_write A after MFMA; single drain barrier (__syncthreads) per
// K-step. Epilogue: LDS-staged coalesced stores + exact per-row s_row/s_col.
// NEW (only delta this round): fused bucket-scatter tail (R1 precedent:
// fused edge-atomic tail cost ~+24us vs ~155us standalone).
// ---------------------------------------------------------------------------
__global__ __launch_bounds__(256, 4) void gemm_mfma_kernel(const float* __restrict__ x,
                                                           const unsigned short* __restrict__ Wt,
                                                           unsigned short* __restrict__ hb,
                                                           const float* __restrict__ a,
                                                           float* __restrict__ s_row,
                                                           float* __restrict__ s_col,
                                                           const int* __restrict__ erow,
                                                           const int* __restrict__ ecol,
                                                           int* __restrict__ cursor,
                                                           int* __restrict__ bucket,
                                                           int M, int E) {
    __shared__ union {
        struct { short As[2][64 * 32]; short Bs[2][256 * 32]; } k;  // 8KB + 32KB = 40KB
        short Cs[32 * 260];                                         // 16.6KB (epilogue)
    } u;

    const int tid  = threadIdx.x;
    const int w    = tid >> 6;
    const int lane = tid & 63;
    const int rowbase = blockIdx.x * 64;

    const int wm = w & 1;     // 32-row half
    const int wn = w >> 1;    // 128-col half
    const int srow = lane >> 2;
    const int skq  = (lane & 3) << 3;
    const int fm = lane & 15;
    const int fq = lane >> 4;

    floatx4 acc[2][8];
#pragma unroll
    for (int i = 0; i < 2; ++i)
#pragma unroll
        for (int j = 0; j < 8; ++j)
            acc[i][j] = (floatx4){0.f, 0.f, 0.f, 0.f};

    // A-staging: wave w owns 16 rows (w*16+srow), 2 float4 per lane per K-step.
    const int arow = min(rowbase + w * 16 + srow, M - 1);
    const size_t abase = (size_t)arow * NFEAT + skq;
    const int lrowA = (w * 16 + srow) * 32 + skq;     // LDS halfword offset within As[buf]

    // B-staging: wave w stages segs 4w..4w+3 (16 n-rows each, 16B/lane).
#define STAGE_B(buf, k0)                                                                      \
    {                                                                                         \
        _Pragma("unroll")                                                                     \
        for (int t = 0; t < 4; ++t) {                                                         \
            const int seg = w * 4 + t;                                                        \
            const int nr  = seg * 16 + srow;                                                  \
            __builtin_amdgcn_global_load_lds(                                                 \
                (const __attribute__((address_space(1))) void*)(Wt + (size_t)nr * NFEAT + (k0) + skq), \
                (__attribute__((address_space(3))) void*)(&u.k.Bs[buf][seg * 512]), 16, 0, 0); \
        }                                                                                     \
    }

    // ---- prologue: fill buffer 0 with k0=0 ----
    STAGE_B(0, 0)
    {
        const float4* xp = (const float4*)&x[abase];
        const float4 u0 = xp[0];
        const float4 u1 = xp[1];
        uint4 o;
        o.x = pack_bf16_rh(u0.x, u0.y);
        o.y = pack_bf16_rh(u0.z, u0.w);
        o.z = pack_bf16_rh(u1.x, u1.y);
        o.w = pack_bf16_rh(u1.z, u1.w);
        *(uint4*)&u.k.As[0][lrowA] = o;
    }
    __syncthreads();

    int cur = 0;
    for (int k0 = 0; k0 < NFEAT; k0 += 32) {
        const int nxt = cur ^ 1;
        const bool have_next = (k0 + 32) < NFEAT;
        float4 p0, p1;
        if (have_next) {
            // Issue next tile's loads FIRST so latency hides under MFMA.
            const float4* xp = (const float4*)&x[abase + k0 + 32];
            p0 = xp[0];
            p1 = xp[1];
            STAGE_B(nxt, k0 + 32)
        }

        short8 af[2];
#pragma unroll
        for (int mt = 0; mt < 2; ++mt)
            af[mt] = *(const short8*)&u.k.As[cur][(wm * 32 + mt * 16 + fm) * 32 + fq * 8];
#pragma unroll
        for (int nt = 0; nt < 8; ++nt) {
            const short8 bfr = *(const short8*)&u.k.Bs[cur][(wn * 128 + nt * 16 + fm) * 32 + fq * 8];
            acc[0][nt] = __builtin_amdgcn_mfma_f32_16x16x32_bf16(af[0], bfr, acc[0][nt], 0, 0, 0);
            acc[1][nt] = __builtin_amdgcn_mfma_f32_16x16x32_bf16(af[1], bfr, acc[1][nt], 0, 0, 0);
        }

        if (have_next) {
            uint4 o;
            o.x = pack_bf16_rh(p0.x, p0.y);
            o.y = pack_bf16_rh(p0.z, p0.w);
            o.z = pack_bf16_rh(p1.x, p1.y);
            o.w = pack_bf16_rh(p1.z, p1.w);
            *(uint4*)&u.k.As[nxt][lrowA] = o;
        }
        __syncthreads();   // drains vmcnt (B lds) + lgkmcnt (A write) for nxt
        cur = nxt;
    }

    // Epilogue: 2 passes of 32 rows through Cs (stride 260).
#pragma unroll
    for (int p = 0; p < 2; ++p) {
        __syncthreads();
        if (wm == p) {
#pragma unroll
            for (int mt = 0; mt < 2; ++mt)
#pragma unroll
                for (int nt = 0; nt < 8; ++nt)
#pragma unroll
                    for (int r = 0; r < 4; ++r)
                        u.Cs[(mt * 16 + fq * 4 + r) * 260 + wn * 128 + nt * 16 + fm] =
                            (short)f2bf(acc[mt][nt][r]);
        }
        __syncthreads();
        // 32 rows x 256 cols: one wave handles one row/iter
#pragma unroll
        for (int kk = 0; kk < 8; ++kk) {
            const int idx = tid + kk * 256;
            const int lrow = idx >> 6;
            const int c4 = (idx & 63) << 2;
            const int grow = rowbase + p * 32 + lrow;
            const uint2 vv = *(const uint2*)&u.Cs[lrow * 260 + c4];
            const float f0 = bf2f_lo(vv.x), f1 = bf2f_hi(vv.x);
            const float f2 = bf2f_lo(vv.y), f3 = bf2f_hi(vv.y);
            const float4 A1 = *(const float4*)&a[c4];
            const float4 A2 = *(const float4*)&a[NCLASS + c4];
            float p1 = f0 * A1.x + f1 * A1.y + f2 * A1.z + f3 * A1.w;
            float p2 = f0 * A2.x + f1 * A2.y + f2 * A2.z + f3 * A2.w;
#pragma unroll
            for (int off = 1; off < 64; off <<= 1) {
                p1 += __shfl_xor(p1, off);
                p2 += __shfl_xor(p2, off);
            }
            if (grow < M) {
                *(uint2*)&hb[(size_t)grow * NCLASS + c4] = vv;
                if (lane == 0) {
                    s_row[grow] = p1;
                    s_col[grow] = p2;
                }
            }
        }
    }

    // Fused bucket-scatter tail: grid-stride over edges. Overlaps across
    // blocks with the latency-bound K-loop/epilogue of other blocks.
    const int gtid = blockIdx.x * 256 + tid;
    for (int i = gtid; i < E; i += GBLK * 256) {
        const int r = erow[i];
        const int c = ecol[i];
        const int pos = atomicAdd(&cursor[r], 1);
        if (pos < BCAP) bucket[((size_t)r << 6) + pos] = c;
    }
}

// ---------------------------------------------------------------------------
// Aggregation + elu + log_softmax (VERIFIED R3 version). One wave per row;
// lane holds 4 features. e = exp(-lrelu(s_row[r] + s_col[c])) inline.
// ---------------------------------------------------------------------------
__global__ __launch_bounds__(256) void aggregate_kernel(const unsigned short* __restrict__ hb,
                                                        const int* __restrict__ bucket,
                                                        const int* __restrict__ cnt,
                                                        const float* __restrict__ s_row,
                                                        const float* __restrict__ s_col,
                                                        float* __restrict__ out, int n) {
    const int wave = (int)((blockIdx.x * (size_t)blockDim.x + threadIdx.x) >> 6);
    const int lane = threadIdx.x & 63;
    if (wave >= n) return;
    const int r = wave;
    const int jb = r << 6;
    const int je = jb + min(cnt[r], BCAP);
    const int fo = lane << 2;
    const float sr = s_row[r];

    float rowsum = 0.f;
    int j = jb;

#define EDGE_E(c) ({ const float _l = sr + s_col[c];                         \
                     const float _lr = _l > 0.f ? _l : NEG_SLOPE * _l;       \
                     __expf(-_lr); })

#ifdef HAVE_DOT2
    float ac0 = 0.f, ac1 = 0.f, ac2 = 0.f, ac3 = 0.f;
    for (; j + 3 < je; j += 4) {
        const int4 cv = *(const int4*)&bucket[j];
        const uint2 g0 = *(const uint2*)&hb[(size_t)cv.x * NCLASS + fo];
        const uint2 g1 = *(const uint2*)&hb[(size_t)cv.y * NCLASS + fo];
        const uint2 g2 = *(const uint2*)&hb[(size_t)cv.z * NCLASS + fo];
        const uint2 g3 = *(const uint2*)&hb[(size_t)cv.w * NCLASS + fo];
        const float e0 = EDGE_E(cv.x);
        const float e1 = EDGE_E(cv.y);
        const float e2 = EDGE_E(cv.z);
        const float e3 = EDGE_E(cv.w);
        const unsigned ep01 = pack_bf16_rh(e0, e1);
        const unsigned ep23 = pack_bf16_rh(e2, e3);
        rowsum += (e0 + e1) + (e2 + e3);
        ac0 = dot2bf(__builtin_amdgcn_perm(g1.x, g0.x, 0x05040100), ep01, ac0);
        ac1 = dot2bf(__builtin_amdgcn_perm(g1.x, g0.x, 0x07060302), ep01, ac1);
        ac2 = dot2bf(__builtin_amdgcn_perm(g1.y, g0.y, 0x05040100), ep01, ac2);
        ac3 = dot2bf(__builtin_amdgcn_perm(g1.y, g0.y, 0x07060302), ep01, ac3);
        ac0 = dot2bf(__builtin_amdgcn_perm(g3.x, g2.x, 0x05040100), ep23, ac0);
        ac1 = dot2bf(__builtin_amdgcn_perm(g3.x, g2.x, 0x07060302), ep23, ac1);
        ac2 = dot2bf(__builtin_amdgcn_perm(g3.y, g2.y, 0x05040100), ep23, ac2);
        ac3 = dot2bf(__builtin_amdgcn_perm(g3.y, g2.y, 0x07060302), ep23, ac3);
    }
    float4 acc = make_float4(ac0, ac1, ac2, ac3);
#else
    float4 acc = make_float4(0.f, 0.f, 0.f, 0.f);
    for (; j + 3 < je; j += 4) {
        const int4 cv = *(const int4*)&bucket[j];
        const uint2 g0 = *(const uint2*)&hb[(size_t)cv.x * NCLASS + fo];
        const uint2 g1 = *(const uint2*)&hb[(size_t)cv.y * NCLASS + fo];
        const uint2 g2 = *(const uint2*)&hb[(size_t)cv.z * NCLASS + fo];
        const uint2 g3 = *(const uint2*)&hb[(size_t)cv.w * NCLASS + fo];
        const float e0 = EDGE_E(cv.x);
        const float e1 = EDGE_E(cv.y);
        const float e2 = EDGE_E(cv.z);
        const float e3 = EDGE_E(cv.w);
        rowsum += (e0 + e1) + (e2 + e3);
        acc.x += e0 * bf2f_lo(g0.x) + e1 * bf2f_lo(g1.x) + e2 * bf2f_lo(g2.x) + e3 * bf2f_lo(g3.x);
        acc.y += e0 * bf2f_hi(g0.x) + e1 * bf2f_hi(g1.x) + e2 * bf2f_hi(g2.x) + e3 * bf2f_hi(g3.x);
        acc.z += e0 * bf2f_lo(g0.y) + e1 * bf2f_lo(g1.y) + e2 * bf2f_lo(g2.y) + e3 * bf2f_lo(g3.y);
        acc.w += e0 * bf2f_hi(g0.y) + e1 * bf2f_hi(g1.y) + e2 * bf2f_hi(g2.y) + e3 * bf2f_hi(g3.y);
    }
#endif
    for (; j < je; ++j) {
        const int c = bucket[j];
        const uint2 g = *(const uint2*)&hb[(size_t)c * NCLASS + fo];
        const float e = EDGE_E(c);
        rowsum += e;
        acc.x += e * bf2f_lo(g.x);
        acc.y += e * bf2f_hi(g.x);
        acc.z += e * bf2f_lo(g.y);
        acc.w += e * bf2f_hi(g.y);
    }

    const float inv = 1.f / rowsum;
    float v[4] = {acc.x * inv, acc.y * inv, acc.z * inv, acc.w * inv};
#pragma unroll
    for (int i = 0; i < 4; ++i)
        v[i] = v[i] > 0.f ? v[i] : __expf(v[i]) - 1.f;

    float m = fmaxf(fmaxf(v[0], v[1]), fmaxf(v[2], v[3]));
#pragma unroll
    for (int off = 32; off > 0; off >>= 1) m = fmaxf(m, __shfl_xor(m, off));
    float s = 0.f;
#pragma unroll
    for (int i = 0; i < 4; ++i) s += __expf(v[i] - m);
#pragma unroll
    for (int off = 32; off > 0; off >>= 1) s += __shfl_xor(s, off);
    const float lse = m + __logf(s);

    float4 o = make_float4(v[0] - lse, v[1] - lse, v[2] - lse, v[3] - lse);
    *(float4*)&out[(size_t)r * NCLASS + fo] = o;
}

// ---------------------------------------------------------------------------
extern "C" void kernel_launch(void* const* d_in, const int* in_sizes, int n_in,
                              void* d_out, int out_size, void* d_ws, size_t ws_size,
                              hipStream_t stream) {
    const float* x  = (const float*)d_in[0];
    const float* W  = (const float*)d_in[1];
    const float* a  = (const float*)d_in[2];
    const int* edge = (const int*)d_in[3];
    float* out = (float*)d_out;

    const int M = in_sizes[0] / NFEAT;         // 50000
    const int E = in_sizes[3] / 2;             // 850000
    const int* row = edge;
    const int* col = edge + E;

    char* ws = (char*)d_ws;
    size_t off = 0;
    auto carve = [&](size_t bytes) -> char* {
        char* p = ws + off;
        off = (off + bytes + 255) & ~(size_t)255;
        return p;
    };
    unsigned short* Wt = (unsigned short*)carve((size_t)NCLASS * NFEAT * sizeof(short));
    unsigned short* hb = (unsigned short*)carve((size_t)M * NCLASS * sizeof(short)); // 25.6MB
    int*   cursor   = (int*)carve((size_t)M * sizeof(int));
    float* s_row    = (float*)carve((size_t)M * sizeof(float));
    float* s_col    = (float*)carve((size_t)M * sizeof(float));
    int*   bucket   = (int*)carve((size_t)M * BCAP * sizeof(int));   // 12.8MB

    init_kernel<<<512, 256, 0, stream>>>(W, Wt, cursor, M);

    gemm_mfma_kernel<<<GBLK, 256, 0, stream>>>(x, Wt, hb, a, s_row, s_col,
                                               row, col, cursor, bucket, M, E);

    aggregate_kernel<<<(M + 3) / 4, 256, 0, stream>>>(hb, bucket, cursor, s_row, s_col, out, M);
}

// Round 6
// 314.142 us; speedup vs baseline: 1.0743x; 1.0023x over previous
//
#include <hip/hip_runtime.h>
#include <math.h>

#define NNODES   50000
#define NFEAT    512
#define NCLASS   256
#define NEG_SLOPE 0.2f
#define GBLK     1564    // 1564 * 32 rows = 50048
#define BCAP     64      // per-row bucket capacity; P(deg>64) ~ 1e-18/row

typedef __attribute__((ext_vector_type(8))) short short8;
typedef __attribute__((ext_vector_type(4))) float floatx4;

__device__ __forceinline__ unsigned short f2bf(float f) {
    unsigned u = __builtin_bit_cast(unsigned, f);
    u += 0x7fffu + ((u >> 16) & 1u);          // RNE
    return (unsigned short)(u >> 16);
}
__device__ __forceinline__ float bf2f_lo(unsigned u) {
    return __builtin_bit_cast(float, u << 16);
}
__device__ __forceinline__ float bf2f_hi(unsigned u) {
    return __builtin_bit_cast(float, u & 0xffff0000u);
}
// pack two floats -> (bf16(lo) | bf16(hi)<<16), round-half-away
__device__ __forceinline__ unsigned pack_bf16_rh(float lo, float hi) {
    const unsigned ulo = __builtin_bit_cast(unsigned, lo) + 0x8000u;
    const unsigned uhi = __builtin_bit_cast(unsigned, hi) + 0x8000u;
    return __builtin_amdgcn_perm(uhi, ulo, 0x07060302);
}

#if __has_builtin(__builtin_amdgcn_fdot2_f32_bf16)
#define HAVE_DOT2 1
typedef __attribute__((ext_vector_type(2))) __bf16 bfx2;
__device__ __forceinline__ float dot2bf(unsigned hpair, unsigned epair, float acc) {
    return __builtin_amdgcn_fdot2_f32_bf16(__builtin_bit_cast(bfx2, hpair),
                                           __builtin_bit_cast(bfx2, epair), acc, false);
}
#endif

// ---------------------------------------------------------------------------
// Init: W [512][256] fp32 -> Wt [256][512] bf16 transposed; zero cursor.
// ---------------------------------------------------------------------------
__global__ __launch_bounds__(256) void init_kernel(const float* __restrict__ W,
                                                   unsigned short* __restrict__ Wt,
                                                   int* __restrict__ cursor, int zn) {
    const int i = blockIdx.x * 256 + threadIdx.x;     // 0..131071
    const int n = i >> 9;
    const int k = i & 511;
    Wt[i] = f2bf(W[(size_t)k * NCLASS + n]);
    if (i < zn) cursor[i] = 0;
}

// ---------------------------------------------------------------------------
// MFMA GEMM (R2-verified template, tile geometry change only):
// 32x256 tile, 1564 blocks (6.1 blocks/CU grid, 4 co-resident via 36KB LDS)
// -> 2x the drain-overlap depth of the 64-row/782-block config.
// 4 waves each own 64 output cols (wn=w), all waves share the 32 rows.
// acc 2x4. Double-buffered LDS, 2-phase pipeline: issue next tile's loads
// (A fp32->regs, B global_load_lds) BEFORE ds_read+MFMA of current buffer;
// pack+ds_write A after MFMA; one __syncthreads per K-step.
// Epilogue: single-pass LDS-staged coalesced stores + per-row s_row/s_col.
// ---------------------------------------------------------------------------
__global__ __launch_bounds__(256, 4) void gemm_mfma_kernel(const float* __restrict__ x,
                                                           const unsigned short* __restrict__ Wt,
                                                           unsigned short* __restrict__ hb,
                                                           const float* __restrict__ a,
                                                           float* __restrict__ s_row,
                                                           float* __restrict__ s_col,
                                                           int M) {
    __shared__ union {
        struct { short As[2][32 * 32]; short Bs[2][256 * 32]; } k;  // 4KB + 32KB = 36KB
        short Cs[32 * 260];                                         // 16.6KB (epilogue)
    } u;

    const int tid  = threadIdx.x;
    const int w    = tid >> 6;
    const int lane = tid & 63;
    const int rowbase = blockIdx.x * 32;

    const int fm = lane & 15;
    const int fq = lane >> 4;

    floatx4 acc[2][4];
#pragma unroll
    for (int i = 0; i < 2; ++i)
#pragma unroll
        for (int j = 0; j < 4; ++j)
            acc[i][j] = (floatx4){0.f, 0.f, 0.f, 0.f};

    // A-staging: wave w owns rows w*8 + (lane>>3); one float4 (16B) per lane
    // per K-step covering k-chunk (lane&7)*4.
    const int srowA = lane >> 3;              // 0..7
    const int skqA  = (lane & 7) << 2;        // fp32 elem offset 0..28
    const int arow  = min(rowbase + w * 8 + srowA, M - 1);
    const size_t abase = (size_t)arow * NFEAT + skqA;
    const int lrowA = (w * 8 + srowA) * 32 + skqA;   // halfword offset in As[buf]

    // B-staging: wave w stages segs 4w..4w+3 (16 n-rows each, 16B/lane).
    const int srowB = lane >> 2;              // 0..15
    const int skqB  = (lane & 3) << 3;        // halfword offset 0..24
#define STAGE_B(buf, k0)                                                                      \
    {                                                                                         \
        _Pragma("unroll")                                                                     \
        for (int t = 0; t < 4; ++t) {                                                         \
            const int seg = w * 4 + t;                                                        \
            const int nr  = seg * 16 + srowB;                                                 \
            __builtin_amdgcn_global_load_lds(                                                 \
                (const __attribute__((address_space(1))) void*)(Wt + (size_t)nr * NFEAT + (k0) + skqB), \
                (__attribute__((address_space(3))) void*)(&u.k.Bs[buf][seg * 512]), 16, 0, 0); \
        }                                                                                     \
    }

    // ---- prologue: fill buffer 0 with k0=0 ----
    STAGE_B(0, 0)
    {
        const float4 u0 = *(const float4*)&x[abase];
        uint2 o;
        o.x = pack_bf16_rh(u0.x, u0.y);
        o.y = pack_bf16_rh(u0.z, u0.w);
        *(uint2*)&u.k.As[0][lrowA] = o;
    }
    __syncthreads();

    int cur = 0;
    for (int k0 = 0; k0 < NFEAT; k0 += 32) {
        const int nxt = cur ^ 1;
        const bool have_next = (k0 + 32) < NFEAT;
        float4 p0;
        if (have_next) {
            // Issue next tile's loads FIRST so latency hides under MFMA.
            p0 = *(const float4*)&x[abase + k0 + 32];
            STAGE_B(nxt, k0 + 32)
        }

        short8 af[2];
#pragma unroll
        for (int mt = 0; mt < 2; ++mt)
            af[mt] = *(const short8*)&u.k.As[cur][(mt * 16 + fm) * 32 + fq * 8];
#pragma unroll
        for (int nt = 0; nt < 4; ++nt) {
            const short8 bfr = *(const short8*)&u.k.Bs[cur][(w * 64 + nt * 16 + fm) * 32 + fq * 8];
            acc[0][nt] = __builtin_amdgcn_mfma_f32_16x16x32_bf16(af[0], bfr, acc[0][nt], 0, 0, 0);
            acc[1][nt] = __builtin_amdgcn_mfma_f32_16x16x32_bf16(af[1], bfr, acc[1][nt], 0, 0, 0);
        }

        if (have_next) {
            uint2 o;
            o.x = pack_bf16_rh(p0.x, p0.y);
            o.y = pack_bf16_rh(p0.z, p0.w);
            *(uint2*)&u.k.As[nxt][lrowA] = o;
        }
        __syncthreads();   // drains vmcnt (B lds) + lgkmcnt (A write) for nxt
        cur = nxt;
    }

    // Epilogue: single pass of 32 rows through Cs (stride 260).
    __syncthreads();
#pragma unroll
    for (int mt = 0; mt < 2; ++mt)
#pragma unroll
        for (int nt = 0; nt < 4; ++nt)
#pragma unroll
            for (int r = 0; r < 4; ++r)
                u.Cs[(mt * 16 + fq * 4 + r) * 260 + w * 64 + nt * 16 + fm] =
                    (short)f2bf(acc[mt][nt][r]);
    __syncthreads();
    // 32 rows x 256 cols: one wave handles one row/iter
#pragma unroll
    for (int kk = 0; kk < 8; ++kk) {
        const int idx = tid + kk * 256;
        const int lrow = idx >> 6;
        const int c4 = (idx & 63) << 2;
        const int grow = rowbase + lrow;
        const uint2 vv = *(const uint2*)&u.Cs[lrow * 260 + c4];
        const float f0 = bf2f_lo(vv.x), f1 = bf2f_hi(vv.x);
        const float f2 = bf2f_lo(vv.y), f3 = bf2f_hi(vv.y);
        const float4 A1 = *(const float4*)&a[c4];
        const float4 A2 = *(const float4*)&a[NCLASS + c4];
        float p1 = f0 * A1.x + f1 * A1.y + f2 * A1.z + f3 * A1.w;
        float p2 = f0 * A2.x + f1 * A2.y + f2 * A2.z + f3 * A2.w;
#pragma unroll
        for (int off = 1; off < 64; off <<= 1) {
            p1 += __shfl_xor(p1, off);
            p2 += __shfl_xor(p2, off);
        }
        if (grow < M) {
            *(uint2*)&hb[(size_t)grow * NCLASS + c4] = vv;
            if (lane == 0) {
                s_row[grow] = p1;
                s_col[grow] = p2;
            }
        }
    }
}

// ---------------------------------------------------------------------------
// Scatter (VERIFIED R3 standalone): group edges into fixed-capacity per-row
// buckets, col only.
// ---------------------------------------------------------------------------
__global__ __launch_bounds__(256) void scatter_kernel(const int* __restrict__ row,
                                                      const int* __restrict__ col,
                                                      int* __restrict__ cursor,
                                                      int* __restrict__ bucket, int e) {
    const int i = blockIdx.x * 256 + threadIdx.x;
    if (i >= e) return;
    const int r = row[i];
    const int c = col[i];
    const int pos = atomicAdd(&cursor[r], 1);
    if (pos < BCAP) bucket[((size_t)r << 6) + pos] = c;
}

// ---------------------------------------------------------------------------
// Aggregation + elu + log_softmax (VERIFIED R3/R5 version). One wave per row;
// lane holds 4 features. e = exp(-lrelu(s_row[r] + s_col[c])) inline.
// ---------------------------------------------------------------------------
__global__ __launch_bounds__(256) void aggregate_kernel(const unsigned short* __restrict__ hb,
                                                        const int* __restrict__ bucket,
                                                        const int* __restrict__ cnt,
                                                        const float* __restrict__ s_row,
                                                        const float* __restrict__ s_col,
                                                        float* __restrict__ out, int n) {
    const int wave = (int)((blockIdx.x * (size_t)blockDim.x + threadIdx.x) >> 6);
    const int lane = threadIdx.x & 63;
    if (wave >= n) return;
    const int r = wave;
    const int jb = r << 6;
    const int je = jb + min(cnt[r], BCAP);
    const int fo = lane << 2;
    const float sr = s_row[r];

    float rowsum = 0.f;
    int j = jb;

#define EDGE_E(c) ({ const float _l = sr + s_col[c];                         \
                     const float _lr = _l > 0.f ? _l : NEG_SLOPE * _l;       \
                     __expf(-_lr); })

#ifdef HAVE_DOT2
    float ac0 = 0.f, ac1 = 0.f, ac2 = 0.f, ac3 = 0.f;
    for (; j + 3 < je; j += 4) {
        const int4 cv = *(const int4*)&bucket[j];
        const uint2 g0 = *(const uint2*)&hb[(size_t)cv.x * NCLASS + fo];
        const uint2 g1 = *(const uint2*)&hb[(size_t)cv.y * NCLASS + fo];
        const uint2 g2 = *(const uint2*)&hb[(size_t)cv.z * NCLASS + fo];
        const uint2 g3 = *(const uint2*)&hb[(size_t)cv.w * NCLASS + fo];
        const float e0 = EDGE_E(cv.x);
        const float e1 = EDGE_E(cv.y);
        const float e2 = EDGE_E(cv.z);
        const float e3 = EDGE_E(cv.w);
        const unsigned ep01 = pack_bf16_rh(e0, e1);
        const unsigned ep23 = pack_bf16_rh(e2, e3);
        rowsum += (e0 + e1) + (e2 + e3);
        ac0 = dot2bf(__builtin_amdgcn_perm(g1.x, g0.x, 0x05040100), ep01, ac0);
        ac1 = dot2bf(__builtin_amdgcn_perm(g1.x, g0.x, 0x07060302), ep01, ac1);
        ac2 = dot2bf(__builtin_amdgcn_perm(g1.y, g0.y, 0x05040100), ep01, ac2);
        ac3 = dot2bf(__builtin_amdgcn_perm(g1.y, g0.y, 0x07060302), ep01, ac3);
        ac0 = dot2bf(__builtin_amdgcn_perm(g3.x, g2.x, 0x05040100), ep23, ac0);
        ac1 = dot2bf(__builtin_amdgcn_perm(g3.x, g2.x, 0x07060302), ep23, ac1);
        ac2 = dot2bf(__builtin_amdgcn_perm(g3.y, g2.y, 0x05040100), ep23, ac2);
        ac3 = dot2bf(__builtin_amdgcn_perm(g3.y, g2.y, 0x07060302), ep23, ac3);
    }
    float4 acc = make_float4(ac0, ac1, ac2, ac3);
#else
    float4 acc = make_float4(0.f, 0.f, 0.f, 0.f);
    for (; j + 3 < je; j += 4) {
        const int4 cv = *(const int4*)&bucket[j];
        const uint2 g0 = *(const uint2*)&hb[(size_t)cv.x * NCLASS + fo];
        const uint2 g1 = *(const uint2*)&hb[(size_t)cv.y * NCLASS + fo];
        const uint2 g2 = *(const uint2*)&hb[(size_t)cv.z * NCLASS + fo];
        const uint2 g3 = *(const uint2*)&hb[(size_t)cv.w * NCLASS + fo];
        const float e0 = EDGE_E(cv.x);
        const float e1 = EDGE_E(cv.y);
        const float e2 = EDGE_E(cv.z);
        const float e3 = EDGE_E(cv.w);
        rowsum += (e0 + e1) + (e2 + e3);
        acc.x += e0 * bf2f_lo(g0.x) + e1 * bf2f_lo(g1.x) + e2 * bf2f_lo(g2.x) + e3 * bf2f_lo(g3.x);
        acc.y += e0 * bf2f_hi(g0.x) + e1 * bf2f_hi(g1.x) + e2 * bf2f_hi(g2.x) + e3 * bf2f_hi(g3.x);
        acc.z += e0 * bf2f_lo(g0.y) + e1 * bf2f_lo(g1.y) + e2 * bf2f_lo(g2.y) + e3 * bf2f_lo(g3.y);
        acc.w += e0 * bf2f_hi(g0.y) + e1 * bf2f_hi(g1.y) + e2 * bf2f_hi(g2.y) + e3 * bf2f_hi(g3.y);
    }
#endif
    for (; j < je; ++j) {
        const int c = bucket[j];
        const uint2 g = *(const uint2*)&hb[(size_t)c * NCLASS + fo];
        const float e = EDGE_E(c);
        rowsum += e;
        acc.x += e * bf2f_lo(g.x);
        acc.y += e * bf2f_hi(g.x);
        acc.z += e * bf2f_lo(g.y);
        acc.w += e * bf2f_hi(g.y);
    }

    const float inv = 1.f / rowsum;
    float v[4] = {acc.x * inv, acc.y * inv, acc.z * inv, acc.w * inv};
#pragma unroll
    for (int i = 0; i < 4; ++i)
        v[i] = v[i] > 0.f ? v[i] : __expf(v[i]) - 1.f;

    float m = fmaxf(fmaxf(v[0], v[1]), fmaxf(v[2], v[3]));
#pragma unroll
    for (int off = 32; off > 0; off >>= 1) m = fmaxf(m, __shfl_xor(m, off));
    float s = 0.f;
#pragma unroll
    for (int i = 0; i < 4; ++i) s += __expf(v[i] - m);
#pragma unroll
    for (int off = 32; off > 0; off >>= 1) s += __shfl_xor(s, off);
    const float lse = m + __logf(s);

    float4 o = make_float4(v[0] - lse, v[1] - lse, v[2] - lse, v[3] - lse);
    *(float4*)&out[(size_t)r * NCLASS + fo] = o;
}

// ---------------------------------------------------------------------------
extern "C" void kernel_launch(void* const* d_in, const int* in_sizes, int n_in,
                              void* d_out, int out_size, void* d_ws, size_t ws_size,
                              hipStream_t stream) {
    const float* x  = (const float*)d_in[0];
    const float* W  = (const float*)d_in[1];
    const float* a  = (const float*)d_in[2];
    const int* edge = (const int*)d_in[3];
    float* out = (float*)d_out;

    const int M = in_sizes[0] / NFEAT;         // 50000
    const int E = in_sizes[3] / 2;             // 850000
    const int* row = edge;
    const int* col = edge + E;

    char* ws = (char*)d_ws;
    size_t off = 0;
    auto carve = [&](size_t bytes) -> char* {
        char* p = ws + off;
        off = (off + bytes + 255) & ~(size_t)255;
        return p;
    };
    unsigned short* Wt = (unsigned short*)carve((size_t)NCLASS * NFEAT * sizeof(short));
    unsigned short* hb = (unsigned short*)carve((size_t)M * NCLASS * sizeof(short)); // 25.6MB
    int*   cursor   = (int*)carve((size_t)M * sizeof(int));
    float* s_row    = (float*)carve((size_t)M * sizeof(float));
    float* s_col    = (float*)carve((size_t)M * sizeof(float));
    int*   bucket   = (int*)carve((size_t)M * BCAP * sizeof(int));   // 12.8MB

    init_kernel<<<512, 256, 0, stream>>>(W, Wt, cursor, M);

    gemm_mfma_kernel<<<GBLK, 256, 0, stream>>>(x, Wt, hb, a, s_row, s_col, M);

    scatter_kernel<<<(E + 255) / 256, 256, 0, stream>>>(row, col, cursor, bucket, E);

    aggregate_kernel<<<(M + 3) / 4, 256, 0, stream>>>(hb, bucket, cursor, s_row, s_col, out, M);
}

// Round 7
// 310.581 us; speedup vs baseline: 1.0866x; 1.0115x over previous
//
#include <hip/hip_runtime.h>
#include <math.h>

#define NNODES   50000
#define NFEAT    512
#define NCLASS   256
#define NEG_SLOPE 0.2f
#define GBLK     782     // 782 * 64 rows = 50048
#define BCAP     64      // per-row bucket capacity; P(deg>64) ~ 1e-18/row

typedef __attribute__((ext_vector_type(8))) short short8;
typedef __attribute__((ext_vector_type(4))) float floatx4;

__device__ __forceinline__ unsigned short f2bf(float f) {
    unsigned u = __builtin_bit_cast(unsigned, f);
    u += 0x7fffu + ((u >> 16) & 1u);          // RNE
    return (unsigned short)(u >> 16);
}
__device__ __forceinline__ float bf2f_lo(unsigned u) {
    return __builtin_bit_cast(float, u << 16);
}
__device__ __forceinline__ float bf2f_hi(unsigned u) {
    return __builtin_bit_cast(float, u & 0xffff0000u);
}
// pack two floats -> (bf16(lo) | bf16(hi)<<16), round-half-away
__device__ __forceinline__ unsigned pack_bf16_rh(float lo, float hi) {
    const unsigned ulo = __builtin_bit_cast(unsigned, lo) + 0x8000u;
    const unsigned uhi = __builtin_bit_cast(unsigned, hi) + 0x8000u;
    return __builtin_amdgcn_perm(uhi, ulo, 0x07060302);
}

#if __has_builtin(__builtin_amdgcn_fdot2_f32_bf16)
#define HAVE_DOT2 1
typedef __attribute__((ext_vector_type(2))) __bf16 bfx2;
__device__ __forceinline__ float dot2bf(unsigned hpair, unsigned epair, float acc) {
    return __builtin_amdgcn_fdot2_f32_bf16(__builtin_bit_cast(bfx2, hpair),
                                           __builtin_bit_cast(bfx2, epair), acc, false);
}
#endif

// ---------------------------------------------------------------------------
// Init: W [512][256] fp32 -> Wt [256][512] bf16 transposed; zero cursor.
// ---------------------------------------------------------------------------
__global__ __launch_bounds__(256) void init_kernel(const float* __restrict__ W,
                                                   unsigned short* __restrict__ Wt,
                                                   int* __restrict__ cursor, int zn) {
    const int i = blockIdx.x * 256 + threadIdx.x;     // 0..131071
    const int n = i >> 9;
    const int k = i & 511;
    Wt[i] = f2bf(W[(size_t)k * NCLASS + n]);
    if (i < zn) cursor[i] = 0;
}

// ---------------------------------------------------------------------------
// MFMA GEMM, A-in-registers variant of the VERIFIED R2 template:
// 64x256 tile, 782 blocks, 4 waves; wave w owns rows [w*16, w*16+16) x all
// 256 cols. A (per lane: row w*16+fm, all K) lives in af[16] short8 = 64
// VGPR, loaded once in the prologue (same coalesced pattern as R2 staging)
// -> the K-loop carries ZERO A traffic and no ds_write.
// K-loop (R2's verified single-barrier dbuf): STAGE_B(nxt) -> 16 ds_read +
// 16 MFMA vs af[kk] -> __syncthreads. Fully unrolled (af/acc static-indexed).
// LDS 32KB. Epilogue: verified Cs-staged store path, 2 passes of 32 rows.
// Model test: latency-bound -> ~35-45us; port-cap-bound -> ~55-60us.
// ---------------------------------------------------------------------------
__global__ __launch_bounds__(256, 2) void gemm_mfma_kernel(const float* __restrict__ x,
                                                           const unsigned short* __restrict__ Wt,
                                                           unsigned short* __restrict__ hb,
                                                           const float* __restrict__ a,
                                                           float* __restrict__ s_row,
                                                           float* __restrict__ s_col,
                                                           int M) {
    __shared__ union {
        short Bs[2][256 * 32];   // 32KB dbuf
        short Cs[32 * 260];      // 16.6KB (epilogue)
    } u;

    const int tid  = threadIdx.x;
    const int w    = tid >> 6;
    const int lane = tid & 63;
    const int rowbase = blockIdx.x * 64;

    const int fm = lane & 15;
    const int fq = lane >> 4;

    // ---- A prologue: row (w*16+fm), k-lanes fq*8 within each 32-chunk ----
    const int arow = min(rowbase + w * 16 + fm, M - 1);
    const float* xrow = x + (size_t)arow * NFEAT + fq * 8;
    short8 af[16];
#pragma unroll
    for (int kk = 0; kk < 16; ++kk) {
        const float4 a0 = *(const float4*)(xrow + kk * 32);
        const float4 a1 = *(const float4*)(xrow + kk * 32 + 4);
        uint4 o;
        o.x = pack_bf16_rh(a0.x, a0.y);
        o.y = pack_bf16_rh(a0.z, a0.w);
        o.z = pack_bf16_rh(a1.x, a1.y);
        o.w = pack_bf16_rh(a1.z, a1.w);
        af[kk] = __builtin_bit_cast(short8, o);
    }

    floatx4 acc[16];
#pragma unroll
    for (int nt = 0; nt < 16; ++nt)
        acc[nt] = (floatx4){0.f, 0.f, 0.f, 0.f};

    // B-staging (VERIFIED R2 macro): wave w stages segs 4w..4w+3.
    const int srow = lane >> 2;
    const int skq  = (lane & 3) << 3;
#define STAGE_B(buf, k0)                                                                      \
    {                                                                                         \
        _Pragma("unroll")                                                                     \
        for (int t = 0; t < 4; ++t) {                                                         \
            const int seg = w * 4 + t;                                                        \
            const int nr  = seg * 16 + srow;                                                  \
            __builtin_amdgcn_global_load_lds(                                                 \
                (const __attribute__((address_space(1))) void*)(Wt + (size_t)nr * NFEAT + (k0) + skq), \
                (__attribute__((address_space(3))) void*)(&u.Bs[buf][seg * 512]), 16, 0, 0);  \
        }                                                                                     \
    }

    STAGE_B(0, 0)
    __syncthreads();

#pragma unroll
    for (int kk = 0; kk < 16; ++kk) {
        const int cur = kk & 1;
        if (kk < 15) {
            STAGE_B(cur ^ 1, (kk + 1) * 32)
        }
#pragma unroll
        for (int nt = 0; nt < 16; ++nt) {
            const short8 bfr = *(const short8*)&u.Bs[cur][(nt * 16 + fm) * 32 + fq * 8];
            acc[nt] = __builtin_amdgcn_mfma_f32_16x16x32_bf16(af[kk], bfr, acc[nt], 0, 0, 0);
        }
        __syncthreads();   // drains B DMA for nxt; separates dbuf phases
    }

    // Epilogue (VERIFIED path): 2 passes of 32 rows through Cs (stride 260).
    // Pass p stages waves 2p,2p+1 (rows p*32 .. p*32+31).
#pragma unroll
    for (int p = 0; p < 2; ++p) {
        __syncthreads();
        if ((w >> 1) == p) {
            const int wr = (w & 1) * 16;
#pragma unroll
            for (int nt = 0; nt < 16; ++nt)
#pragma unroll
                for (int r = 0; r < 4; ++r)
                    u.Cs[(wr + fq * 4 + r) * 260 + nt * 16 + fm] = (short)f2bf(acc[nt][r]);
        }
        __syncthreads();
        // 32 rows x 256 cols: one wave handles one row/iter
#pragma unroll
        for (int kk = 0; kk < 8; ++kk) {
            const int idx = tid + kk * 256;
            const int lrow = idx >> 6;
            const int c4 = (idx & 63) << 2;
            const int grow = rowbase + p * 32 + lrow;
            const uint2 vv = *(const uint2*)&u.Cs[lrow * 260 + c4];
            const float f0 = bf2f_lo(vv.x), f1 = bf2f_hi(vv.x);
            const float f2 = bf2f_lo(vv.y), f3 = bf2f_hi(vv.y);
            const float4 A1 = *(const float4*)&a[c4];
            const float4 A2 = *(const float4*)&a[NCLASS + c4];
            float p1 = f0 * A1.x + f1 * A1.y + f2 * A1.z + f3 * A1.w;
            float p2 = f0 * A2.x + f1 * A2.y + f2 * A2.z + f3 * A2.w;
#pragma unroll
            for (int off = 1; off < 64; off <<= 1) {
                p1 += __shfl_xor(p1, off);
                p2 += __shfl_xor(p2, off);
            }
            if (grow < M) {
                *(uint2*)&hb[(size_t)grow * NCLASS + c4] = vv;
                if (lane == 0) {
                    s_row[grow] = p1;
                    s_col[grow] = p2;
                }
            }
        }
    }
}

// ---------------------------------------------------------------------------
// Scatter (VERIFIED): group edges into fixed-capacity per-row buckets.
// ---------------------------------------------------------------------------
__global__ __launch_bounds__(256) void scatter_kernel(const int* __restrict__ row,
                                                      const int* __restrict__ col,
                                                      int* __restrict__ cursor,
                                                      int* __restrict__ bucket, int e) {
    const int i = blockIdx.x * 256 + threadIdx.x;
    if (i >= e) return;
    const int r = row[i];
    const int c = col[i];
    const int pos = atomicAdd(&cursor[r], 1);
    if (pos < BCAP) bucket[((size_t)r << 6) + pos] = c;
}

// ---------------------------------------------------------------------------
// Aggregation + elu + log_softmax (VERIFIED). One wave per row; lane holds
// 4 features. e = exp(-lrelu(s_row[r] + s_col[c])) inline.
// ---------------------------------------------------------------------------
__global__ __launch_bounds__(256) void aggregate_kernel(const unsigned short* __restrict__ hb,
                                                        const int* __restrict__ bucket,
                                                        const int* __restrict__ cnt,
                                                        const float* __restrict__ s_row,
                                                        const float* __restrict__ s_col,
                                                        float* __restrict__ out, int n) {
    const int wave = (int)((blockIdx.x * (size_t)blockDim.x + threadIdx.x) >> 6);
    const int lane = threadIdx.x & 63;
    if (wave >= n) return;
    const int r = wave;
    const int jb = r << 6;
    const int je = jb + min(cnt[r], BCAP);
    const int fo = lane << 2;
    const float sr = s_row[r];

    float rowsum = 0.f;
    int j = jb;

#define EDGE_E(c) ({ const float _l = sr + s_col[c];                         \
                     const float _lr = _l > 0.f ? _l : NEG_SLOPE * _l;       \
                     __expf(-_lr); })

#ifdef HAVE_DOT2
    float ac0 = 0.f, ac1 = 0.f, ac2 = 0.f, ac3 = 0.f;
    for (; j + 3 < je; j += 4) {
        const int4 cv = *(const int4*)&bucket[j];
        const uint2 g0 = *(const uint2*)&hb[(size_t)cv.x * NCLASS + fo];
        const uint2 g1 = *(const uint2*)&hb[(size_t)cv.y * NCLASS + fo];
        const uint2 g2 = *(const uint2*)&hb[(size_t)cv.z * NCLASS + fo];
        const uint2 g3 = *(const uint2*)&hb[(size_t)cv.w * NCLASS + fo];
        const float e0 = EDGE_E(cv.x);
        const float e1 = EDGE_E(cv.y);
        const float e2 = EDGE_E(cv.z);
        const float e3 = EDGE_E(cv.w);
        const unsigned ep01 = pack_bf16_rh(e0, e1);
        const unsigned ep23 = pack_bf16_rh(e2, e3);
        rowsum += (e0 + e1) + (e2 + e3);
        ac0 = dot2bf(__builtin_amdgcn_perm(g1.x, g0.x, 0x05040100), ep01, ac0);
        ac1 = dot2bf(__builtin_amdgcn_perm(g1.x, g0.x, 0x07060302), ep01, ac1);
        ac2 = dot2bf(__builtin_amdgcn_perm(g1.y, g0.y, 0x05040100), ep01, ac2);
        ac3 = dot2bf(__builtin_amdgcn_perm(g1.y, g0.y, 0x07060302), ep01, ac3);
        ac0 = dot2bf(__builtin_amdgcn_perm(g3.x, g2.x, 0x05040100), ep23, ac0);
        ac1 = dot2bf(__builtin_amdgcn_perm(g3.x, g2.x, 0x07060302), ep23, ac1);
        ac2 = dot2bf(__builtin_amdgcn_perm(g3.y, g2.y, 0x05040100), ep23, ac2);
        ac3 = dot2bf(__builtin_amdgcn_perm(g3.y, g2.y, 0x07060302), ep23, ac3);
    }
    float4 acc = make_float4(ac0, ac1, ac2, ac3);
#else
    float4 acc = make_float4(0.f, 0.f, 0.f, 0.f);
    for (; j + 3 < je; j += 4) {
        const int4 cv = *(const int4*)&bucket[j];
        const uint2 g0 = *(const uint2*)&hb[(size_t)cv.x * NCLASS + fo];
        const uint2 g1 = *(const uint2*)&hb[(size_t)cv.y * NCLASS + fo];
        const uint2 g2 = *(const uint2*)&hb[(size_t)cv.z * NCLASS + fo];
        const uint2 g3 = *(const uint2*)&hb[(size_t)cv.w * NCLASS + fo];
        const float e0 = EDGE_E(cv.x);
        const float e1 = EDGE_E(cv.y);
        const float e2 = EDGE_E(cv.z);
        const float e3 = EDGE_E(cv.w);
        rowsum += (e0 + e1) + (e2 + e3);
        acc.x += e0 * bf2f_lo(g0.x) + e1 * bf2f_lo(g1.x) + e2 * bf2f_lo(g2.x) + e3 * bf2f_lo(g3.x);
        acc.y += e0 * bf2f_hi(g0.x) + e1 * bf2f_hi(g1.x) + e2 * bf2f_hi(g2.x) + e3 * bf2f_hi(g3.x);
        acc.z += e0 * bf2f_lo(g0.y) + e1 * bf2f_lo(g1.y) + e2 * bf2f_lo(g2.y) + e3 * bf2f_lo(g3.y);
        acc.w += e0 * bf2f_hi(g0.y) + e1 * bf2f_hi(g1.y) + e2 * bf2f_hi(g2.y) + e3 * bf2f_hi(g3.y);
    }
#endif
    for (; j < je; ++j) {
        const int c = bucket[j];
        const uint2 g = *(const uint2*)&hb[(size_t)c * NCLASS + fo];
        const float e = EDGE_E(c);
        rowsum += e;
        acc.x += e * bf2f_lo(g.x);
        acc.y += e * bf2f_hi(g.x);
        acc.z += e * bf2f_lo(g.y);
        acc.w += e * bf2f_hi(g.y);
    }

    const float inv = 1.f / rowsum;
    float v[4] = {acc.x * inv, acc.y * inv, acc.z * inv, acc.w * inv};
#pragma unroll
    for (int i = 0; i < 4; ++i)
        v[i] = v[i] > 0.f ? v[i] : __expf(v[i]) - 1.f;

    float m = fmaxf(fmaxf(v[0], v[1]), fmaxf(v[2], v[3]));
#pragma unroll
    for (int off = 32; off > 0; off >>= 1) m = fmaxf(m, __shfl_xor(m, off));
    float s = 0.f;
#pragma unroll
    for (int i = 0; i < 4; ++i) s += __expf(v[i] - m);
#pragma unroll
    for (int off = 32; off > 0; off >>= 1) s += __shfl_xor(s, off);
    const float lse = m + __logf(s);

    float4 o = make_float4(v[0] - lse, v[1] - lse, v[2] - lse, v[3] - lse);
    *(float4*)&out[(size_t)r * NCLASS + fo] = o;
}

// ---------------------------------------------------------------------------
extern "C" void kernel_launch(void* const* d_in, const int* in_sizes, int n_in,
                              void* d_out, int out_size, void* d_ws, size_t ws_size,
                              hipStream_t stream) {
    const float* x  = (const float*)d_in[0];
    const float* W  = (const float*)d_in[1];
    const float* a  = (const float*)d_in[2];
    const int* edge = (const int*)d_in[3];
    float* out = (float*)d_out;

    const int M = in_sizes[0] / NFEAT;         // 50000
    const int E = in_sizes[3] / 2;             // 850000
    const int* row = edge;
    const int* col = edge + E;

    char* ws = (char*)d_ws;
    size_t off = 0;
    auto carve = [&](size_t bytes) -> char* {
        char* p = ws + off;
        off = (off + bytes + 255) & ~(size_t)255;
        return p;
    };
    unsigned short* Wt = (unsigned short*)carve((size_t)NCLASS * NFEAT * sizeof(short));
    unsigned short* hb = (unsigned short*)carve((size_t)M * NCLASS * sizeof(short)); // 25.6MB
    int*   cursor   = (int*)carve((size_t)M * sizeof(int));
    float* s_row    = (float*)carve((size_t)M * sizeof(float));
    float* s_col    = (float*)carve((size_t)M * sizeof(float));
    int*   bucket   = (int*)carve((size_t)M * BCAP * sizeof(int));   // 12.8MB

    init_kernel<<<512, 256, 0, stream>>>(W, Wt, cursor, M);

    gemm_mfma_kernel<<<GBLK, 256, 0, stream>>>(x, Wt, hb, a, s_row, s_col, M);

    scatter_kernel<<<(E + 255) / 256, 256, 0, stream>>>(row, col, cursor, bucket, E);

    aggregate_kernel<<<(M + 3) / 4, 256, 0, stream>>>(hb, bucket, cursor, s_row, s_col, out, M);
}

// Round 8
// 301.562 us; speedup vs baseline: 1.1191x; 1.0299x over previous
//
#include <hip/hip_runtime.h>
#include <math.h>

#define NNODES   50000
#define NFEAT    512
#define NCLASS   256
#define NEG_SLOPE 0.2f
#define GBLK     782     // gemm-role blocks: 782 * 64 rows = 50048
#define BCAP     64      // per-row bucket capacity; P(deg>64) ~ 1e-18/row

typedef __attribute__((ext_vector_type(8))) short short8;
typedef __attribute__((ext_vector_type(4))) float floatx4;

__device__ __forceinline__ unsigned short f2bf(float f) {
    unsigned u = __builtin_bit_cast(unsigned, f);
    u += 0x7fffu + ((u >> 16) & 1u);          // RNE
    return (unsigned short)(u >> 16);
}
__device__ __forceinline__ float bf2f_lo(unsigned u) {
    return __builtin_bit_cast(float, u << 16);
}
__device__ __forceinline__ float bf2f_hi(unsigned u) {
    return __builtin_bit_cast(float, u & 0xffff0000u);
}
// pack two floats -> (bf16(lo) | bf16(hi)<<16), round-half-away
__device__ __forceinline__ unsigned pack_bf16_rh(float lo, float hi) {
    const unsigned ulo = __builtin_bit_cast(unsigned, lo) + 0x8000u;
    const unsigned uhi = __builtin_bit_cast(unsigned, hi) + 0x8000u;
    return __builtin_amdgcn_perm(uhi, ulo, 0x07060302);
}

#if __has_builtin(__builtin_amdgcn_fdot2_f32_bf16)
#define HAVE_DOT2 1
typedef __attribute__((ext_vector_type(2))) __bf16 bfx2;
__device__ __forceinline__ float dot2bf(unsigned hpair, unsigned epair, float acc) {
    return __builtin_amdgcn_fdot2_f32_bf16(__builtin_bit_cast(bfx2, hpair),
                                           __builtin_bit_cast(bfx2, epair), acc, false);
}
#endif

// ---------------------------------------------------------------------------
// Init: W [512][256] fp32 -> Wt [256][512] bf16 transposed; zero cursor.
// ---------------------------------------------------------------------------
__global__ __launch_bounds__(256) void init_kernel(const float* __restrict__ W,
                                                   unsigned short* __restrict__ Wt,
                                                   int* __restrict__ cursor, int zn) {
    const int i = blockIdx.x * 256 + threadIdx.x;     // 0..131071
    const int n = i >> 9;
    const int k = i & 511;
    Wt[i] = f2bf(W[(size_t)k * NCLASS + n]);
    if (i < zn) cursor[i] = 0;
}

// ---------------------------------------------------------------------------
// Fused heterogeneous dispatch: 1564 blocks.
//   even blocks (bid&1==0): VERIFIED R2 gemm, tile rowbase = (bid>>1)*64.
//   odd  blocks (bid&1==1): VERIFIED scatter, grid-stride over 850K edges.
// The two roles are data-independent (scatter needs only edge lists +
// zeroed cursor). Co-residency (2 gemm + 2 scatter blocks per CU under the
// 40KB LDS cap) lets scatter waves issue during the gemm's barrier stalls
// -- the m114 cross-wave co-schedule effect, applied across roles. R5
// showed a per-block serial tail gives ZERO overlap (134 = 68+62); this
// block-level split is the corrected form.
// Role branch is block-uniform: no divergence, no shared synchronization.
// ---------------------------------------------------------------------------
__global__ __launch_bounds__(256, 4) void gemm_scatter_kernel(const float* __restrict__ x,
                                                              const unsigned short* __restrict__ Wt,
                                                              unsigned short* __restrict__ hb,
                                                              const float* __restrict__ a,
                                                              float* __restrict__ s_row,
                                                              float* __restrict__ s_col,
                                                              const int* __restrict__ erow,
                                                              const int* __restrict__ ecol,
                                                              int* __restrict__ cursor,
                                                              int* __restrict__ bucket,
                                                              int M, int E) {
    __shared__ union {
        struct { short As[2][64 * 32]; short Bs[2][256 * 32]; } k;  // 8KB + 32KB = 40KB
        short Cs[32 * 260];                                         // 16.6KB (epilogue)
    } u;

    const int bid = blockIdx.x;
    const int tid = threadIdx.x;

    if (bid & 1) {
        // ---------------- scatter role (VERIFIED logic, grid-stride) -------
        const int sbid = bid >> 1;                 // 0..781
        const int stride = GBLK * 256;
        for (int i = sbid * 256 + tid; i < E; i += stride) {
            const int r = erow[i];
            const int c = ecol[i];
            const int pos = atomicAdd(&cursor[r], 1);
            if (pos < BCAP) bucket[((size_t)r << 6) + pos] = c;
        }
        return;
    }

    // ---------------- gemm role (byte-identical VERIFIED R2 body) ----------
    const int w    = tid >> 6;
    const int lane = tid & 63;
    const int rowbase = (bid >> 1) * 64;

    const int wm = w & 1;     // 32-row half
    const int wn = w >> 1;    // 128-col half
    const int srow = lane >> 2;
    const int skq  = (lane & 3) << 3;
    const int fm = lane & 15;
    const int fq = lane >> 4;

    floatx4 acc[2][8];
#pragma unroll
    for (int i = 0; i < 2; ++i)
#pragma unroll
        for (int j = 0; j < 8; ++j)
            acc[i][j] = (floatx4){0.f, 0.f, 0.f, 0.f};

    // A-staging: wave w owns 16 rows (w*16+srow), 2 float4 per lane per K-step.
    const int arow = min(rowbase + w * 16 + srow, M - 1);
    const size_t abase = (size_t)arow * NFEAT + skq;
    const int lrowA = (w * 16 + srow) * 32 + skq;     // LDS halfword offset within As[buf]

    // B-staging: wave w stages segs 4w..4w+3 (16 n-rows each, 16B/lane).
#define STAGE_B(buf, k0)                                                                      \
    {                                                                                         \
        _Pragma("unroll")                                                                     \
        for (int t = 0; t < 4; ++t) {                                                         \
            const int seg = w * 4 + t;                                                        \
            const int nr  = seg * 16 + srow;                                                  \
            __builtin_amdgcn_global_load_lds(                                                 \
                (const __attribute__((address_space(1))) void*)(Wt + (size_t)nr * NFEAT + (k0) + skq), \
                (__attribute__((address_space(3))) void*)(&u.k.Bs[buf][seg * 512]), 16, 0, 0); \
        }                                                                                     \
    }

    // ---- prologue: fill buffer 0 with k0=0 ----
    STAGE_B(0, 0)
    {
        const float4* xp = (const float4*)&x[abase];
        const float4 u0 = xp[0];
        const float4 u1 = xp[1];
        uint4 o;
        o.x = pack_bf16_rh(u0.x, u0.y);
        o.y = pack_bf16_rh(u0.z, u0.w);
        o.z = pack_bf16_rh(u1.x, u1.y);
        o.w = pack_bf16_rh(u1.z, u1.w);
        *(uint4*)&u.k.As[0][lrowA] = o;
    }
    __syncthreads();

    int cur = 0;
    for (int k0 = 0; k0 < NFEAT; k0 += 32) {
        const int nxt = cur ^ 1;
        const bool have_next = (k0 + 32) < NFEAT;
        float4 p0, p1;
        if (have_next) {
            // Issue next tile's loads FIRST so latency hides under MFMA.
            const float4* xp = (const float4*)&x[abase + k0 + 32];
            p0 = xp[0];
            p1 = xp[1];
            STAGE_B(nxt, k0 + 32)
        }

        short8 af[2];
#pragma unroll
        for (int mt = 0; mt < 2; ++mt)
            af[mt] = *(const short8*)&u.k.As[cur][(wm * 32 + mt * 16 + fm) * 32 + fq * 8];
#pragma unroll
        for (int nt = 0; nt < 8; ++nt) {
            const short8 bfr = *(const short8*)&u.k.Bs[cur][(wn * 128 + nt * 16 + fm) * 32 + fq * 8];
            acc[0][nt] = __builtin_amdgcn_mfma_f32_16x16x32_bf16(af[0], bfr, acc[0][nt], 0, 0, 0);
            acc[1][nt] = __builtin_amdgcn_mfma_f32_16x16x32_bf16(af[1], bfr, acc[1][nt], 0, 0, 0);
        }

        if (have_next) {
            uint4 o;
            o.x = pack_bf16_rh(p0.x, p0.y);
            o.y = pack_bf16_rh(p0.z, p0.w);
            o.z = pack_bf16_rh(p1.x, p1.y);
            o.w = pack_bf16_rh(p1.z, p1.w);
            *(uint4*)&u.k.As[nxt][lrowA] = o;
        }
        __syncthreads();   // drains vmcnt (B lds) + lgkmcnt (A write) for nxt
        cur = nxt;
    }

    // Epilogue: 2 passes of 32 rows through Cs (stride 260).
#pragma unroll
    for (int p = 0; p < 2; ++p) {
        __syncthreads();
        if (wm == p) {
#pragma unroll
            for (int mt = 0; mt < 2; ++mt)
#pragma unroll
                for (int nt = 0; nt < 8; ++nt)
#pragma unroll
                    for (int r = 0; r < 4; ++r)
                        u.Cs[(mt * 16 + fq * 4 + r) * 260 + wn * 128 + nt * 16 + fm] =
                            (short)f2bf(acc[mt][nt][r]);
        }
        __syncthreads();
        // 32 rows x 256 cols: one wave handles one row/iter
#pragma unroll
        for (int kk = 0; kk < 8; ++kk) {
            const int idx = tid + kk * 256;
            const int lrow = idx >> 6;
            const int c4 = (idx & 63) << 2;
            const int grow = rowbase + p * 32 + lrow;
            const uint2 vv = *(const uint2*)&u.Cs[lrow * 260 + c4];
            const float f0 = bf2f_lo(vv.x), f1 = bf2f_hi(vv.x);
            const float f2 = bf2f_lo(vv.y), f3 = bf2f_hi(vv.y);
            const float4 A1 = *(const float4*)&a[c4];
            const float4 A2 = *(const float4*)&a[NCLASS + c4];
            float p1 = f0 * A1.x + f1 * A1.y + f2 * A1.z + f3 * A1.w;
            float p2 = f0 * A2.x + f1 * A2.y + f2 * A2.z + f3 * A2.w;
#pragma unroll
            for (int off = 1; off < 64; off <<= 1) {
                p1 += __shfl_xor(p1, off);
                p2 += __shfl_xor(p2, off);
            }
            if (grow < M) {
                *(uint2*)&hb[(size_t)grow * NCLASS + c4] = vv;
                if (lane == 0) {
                    s_row[grow] = p1;
                    s_col[grow] = p2;
                }
            }
        }
    }
}

// ---------------------------------------------------------------------------
// Aggregation + elu + log_softmax (VERIFIED). One wave per row; lane holds
// 4 features. e = exp(-lrelu(s_row[r] + s_col[c])) inline.
// ---------------------------------------------------------------------------
__global__ __launch_bounds__(256) void aggregate_kernel(const unsigned short* __restrict__ hb,
                                                        const int* __restrict__ bucket,
                                                        const int* __restrict__ cnt,
                                                        const float* __restrict__ s_row,
                                                        const float* __restrict__ s_col,
                                                        float* __restrict__ out, int n) {
    const int wave = (int)((blockIdx.x * (size_t)blockDim.x + threadIdx.x) >> 6);
    const int lane = threadIdx.x & 63;
    if (wave >= n) return;
    const int r = wave;
    const int jb = r << 6;
    const int je = jb + min(cnt[r], BCAP);
    const int fo = lane << 2;
    const float sr = s_row[r];

    float rowsum = 0.f;
    int j = jb;

#define EDGE_E(c) ({ const float _l = sr + s_col[c];                         \
                     const float _lr = _l > 0.f ? _l : NEG_SLOPE * _l;       \
                     __expf(-_lr); })

#ifdef HAVE_DOT2
    float ac0 = 0.f, ac1 = 0.f, ac2 = 0.f, ac3 = 0.f;
    for (; j + 3 < je; j += 4) {
        const int4 cv = *(const int4*)&bucket[j];
        const uint2 g0 = *(const uint2*)&hb[(size_t)cv.x * NCLASS + fo];
        const uint2 g1 = *(const uint2*)&hb[(size_t)cv.y * NCLASS + fo];
        const uint2 g2 = *(const uint2*)&hb[(size_t)cv.z * NCLASS + fo];
        const uint2 g3 = *(const uint2*)&hb[(size_t)cv.w * NCLASS + fo];
        const float e0 = EDGE_E(cv.x);
        const float e1 = EDGE_E(cv.y);
        const float e2 = EDGE_E(cv.z);
        const float e3 = EDGE_E(cv.w);
        const unsigned ep01 = pack_bf16_rh(e0, e1);
        const unsigned ep23 = pack_bf16_rh(e2, e3);
        rowsum += (e0 + e1) + (e2 + e3);
        ac0 = dot2bf(__builtin_amdgcn_perm(g1.x, g0.x, 0x05040100), ep01, ac0);
        ac1 = dot2bf(__builtin_amdgcn_perm(g1.x, g0.x, 0x07060302), ep01, ac1);
        ac2 = dot2bf(__builtin_amdgcn_perm(g1.y, g0.y, 0x05040100), ep01, ac2);
        ac3 = dot2bf(__builtin_amdgcn_perm(g1.y, g0.y, 0x07060302), ep01, ac3);
        ac0 = dot2bf(__builtin_amdgcn_perm(g3.x, g2.x, 0x05040100), ep23, ac0);
        ac1 = dot2bf(__builtin_amdgcn_perm(g3.x, g2.x, 0x07060302), ep23, ac1);
        ac2 = dot2bf(__builtin_amdgcn_perm(g3.y, g2.y, 0x05040100), ep23, ac2);
        ac3 = dot2bf(__builtin_amdgcn_perm(g3.y, g2.y, 0x07060302), ep23, ac3);
    }
    float4 acc = make_float4(ac0, ac1, ac2, ac3);
#else
    float4 acc = make_float4(0.f, 0.f, 0.f, 0.f);
    for (; j + 3 < je; j += 4) {
        const int4 cv = *(const int4*)&bucket[j];
        const uint2 g0 = *(const uint2*)&hb[(size_t)cv.x * NCLASS + fo];
        const uint2 g1 = *(const uint2*)&hb[(size_t)cv.y * NCLASS + fo];
        const uint2 g2 = *(const uint2*)&hb[(size_t)cv.z * NCLASS + fo];
        const uint2 g3 = *(const uint2*)&hb[(size_t)cv.w * NCLASS + fo];
        const float e0 = EDGE_E(cv.x);
        const float e1 = EDGE_E(cv.y);
        const float e2 = EDGE_E(cv.z);
        const float e3 = EDGE_E(cv.w);
        rowsum += (e0 + e1) + (e2 + e3);
        acc.x += e0 * bf2f_lo(g0.x) + e1 * bf2f_lo(g1.x) + e2 * bf2f_lo(g2.x) + e3 * bf2f_lo(g3.x);
        acc.y += e0 * bf2f_hi(g0.x) + e1 * bf2f_hi(g1.x) + e2 * bf2f_hi(g2.x) + e3 * bf2f_hi(g3.x);
        acc.z += e0 * bf2f_lo(g0.y) + e1 * bf2f_lo(g1.y) + e2 * bf2f_lo(g2.y) + e3 * bf2f_lo(g3.y);
        acc.w += e0 * bf2f_hi(g0.y) + e1 * bf2f_hi(g1.y) + e2 * bf2f_hi(g2.y) + e3 * bf2f_hi(g3.y);
    }
#endif
    for (; j < je; ++j) {
        const int c = bucket[j];
        const uint2 g = *(const uint2*)&hb[(size_t)c * NCLASS + fo];
        const float e = EDGE_E(c);
        rowsum += e;
        acc.x += e * bf2f_lo(g.x);
        acc.y += e * bf2f_hi(g.x);
        acc.z += e * bf2f_lo(g.y);
        acc.w += e * bf2f_hi(g.y);
    }

    const float inv = 1.f / rowsum;
    float v[4] = {acc.x * inv, acc.y * inv, acc.z * inv, acc.w * inv};
#pragma unroll
    for (int i = 0; i < 4; ++i)
        v[i] = v[i] > 0.f ? v[i] : __expf(v[i]) - 1.f;

    float m = fmaxf(fmaxf(v[0], v[1]), fmaxf(v[2], v[3]));
#pragma unroll
    for (int off = 32; off > 0; off >>= 1) m = fmaxf(m, __shfl_xor(m, off));
    float s = 0.f;
#pragma unroll
    for (int i = 0; i < 4; ++i) s += __expf(v[i] - m);
#pragma unroll
    for (int off = 32; off > 0; off >>= 1) s += __shfl_xor(s, off);
    const float lse = m + __logf(s);

    float4 o = make_float4(v[0] - lse, v[1] - lse, v[2] - lse, v[3] - lse);
    *(float4*)&out[(size_t)r * NCLASS + fo] = o;
}

// ---------------------------------------------------------------------------
extern "C" void kernel_launch(void* const* d_in, const int* in_sizes, int n_in,
                              void* d_out, int out_size, void* d_ws, size_t ws_size,
                              hipStream_t stream) {
    const float* x  = (const float*)d_in[0];
    const float* W  = (const float*)d_in[1];
    const float* a  = (const float*)d_in[2];
    const int* edge = (const int*)d_in[3];
    float* out = (float*)d_out;

    const int M = in_sizes[0] / NFEAT;         // 50000
    const int E = in_sizes[3] / 2;             // 850000
    const int* row = edge;
    const int* col = edge + E;

    char* ws = (char*)d_ws;
    size_t off = 0;
    auto carve = [&](size_t bytes) -> char* {
        char* p = ws + off;
        off = (off + bytes + 255) & ~(size_t)255;
        return p;
    };
    unsigned short* Wt = (unsigned short*)carve((size_t)NCLASS * NFEAT * sizeof(short));
    unsigned short* hb = (unsigned short*)carve((size_t)M * NCLASS * sizeof(short)); // 25.6MB
    int*   cursor   = (int*)carve((size_t)M * sizeof(int));
    float* s_row    = (float*)carve((size_t)M * sizeof(float));
    float* s_col    = (float*)carve((size_t)M * sizeof(float));
    int*   bucket   = (int*)carve((size_t)M * BCAP * sizeof(int));   // 12.8MB

    init_kernel<<<512, 256, 0, stream>>>(W, Wt, cursor, M);

    gemm_scatter_kernel<<<2 * GBLK, 256, 0, stream>>>(x, Wt, hb, a, s_row, s_col,
                                                      row, col, cursor, bucket, M, E);

    aggregate_kernel<<<(M + 3) / 4, 256, 0, stream>>>(hb, bucket, cursor, s_row, s_col, out, M);
}

// Round 10
// 282.477 us; speedup vs baseline: 1.1947x; 1.0676x over previous
//
#include <hip/hip_runtime.h>
#include <math.h>

#define NNODES   50000
#define NFEAT    512
#define NCLASS   256
#define NEG_SLOPE 0.2f
#define GBLK     782     // gemm-role blocks: 782 * 64 rows = 50048
#define SBLK     196     // scatter-role blocks (1:4 ratio, placed first)
#define BCAP     64      // per-row bucket capacity; P(deg>64) ~ 1e-18/row

typedef __attribute__((ext_vector_type(8))) short short8;
typedef __attribute__((ext_vector_type(4))) float floatx4;

__device__ __forceinline__ unsigned short f2bf(float f) {
    unsigned u = __builtin_bit_cast(unsigned, f);
    u += 0x7fffu + ((u >> 16) & 1u);          // RNE
    return (unsigned short)(u >> 16);
}
__device__ __forceinline__ float bf2f_lo(unsigned u) {
    return __builtin_bit_cast(float, u << 16);
}
__device__ __forceinline__ float bf2f_hi(unsigned u) {
    return __builtin_bit_cast(float, u & 0xffff0000u);
}
// pack two floats -> (bf16(lo) | bf16(hi)<<16), round-half-away
__device__ __forceinline__ unsigned pack_bf16_rh(float lo, float hi) {
    const unsigned ulo = __builtin_bit_cast(unsigned, lo) + 0x8000u;
    const unsigned uhi = __builtin_bit_cast(unsigned, hi) + 0x8000u;
    return __builtin_amdgcn_perm(uhi, ulo, 0x07060302);
}

#if __has_builtin(__builtin_amdgcn_fdot2_f32_bf16)
#define HAVE_DOT2 1
typedef __attribute__((ext_vector_type(2))) __bf16 bfx2;
__device__ __forceinline__ float dot2bf(unsigned hpair, unsigned epair, float acc) {
    return __builtin_amdgcn_fdot2_f32_bf16(__builtin_bit_cast(bfx2, hpair),
                                           __builtin_bit_cast(bfx2, epair), acc, false);
}
#endif

// ---------------------------------------------------------------------------
// Init: W [512][256] fp32 -> Wt [256][512] bf16 transposed; zero cursor.
// ---------------------------------------------------------------------------
__global__ __launch_bounds__(256) void init_kernel(const float* __restrict__ W,
                                                   unsigned short* __restrict__ Wt,
                                                   int* __restrict__ cursor, int zn) {
    const int i = blockIdx.x * 256 + threadIdx.x;     // 0..131071
    const int n = i >> 9;
    const int k = i & 511;
    Wt[i] = f2bf(W[(size_t)k * NCLASS + n]);
    if (i < zn) cursor[i] = 0;
}

// ---------------------------------------------------------------------------
// Fused heterogeneous dispatch: 978 blocks = 196 scatter (FIRST, for early
// co-residency) + 782 gemm.
// R8 post-mortem: 1:1 interleave starved gemm of residency slots (2 gemm +
// 2 scatter per CU under the 40KB LDS cap) -> fused 115us. This 1:4 ratio
// gives a typical CU 3-4 gemm blocks + <=1 scatter block: gemm runs at its
// standalone concurrency, scatter fills the stall bubbles.
// Roles are data-independent; role branch is block-uniform.
// ---------------------------------------------------------------------------
__global__ __launch_bounds__(256, 4) void gemm_scatter_kernel(const float* __restrict__ x,
                                                              const unsigned short* __restrict__ Wt,
                                                              unsigned short* __restrict__ hb,
                                                              const float* __restrict__ a,
                                                              float* __restrict__ s_row,
                                                              float* __restrict__ s_col,
                                                              const int* __restrict__ erow,
                                                              const int* __restrict__ ecol,
                                                              int* __restrict__ cursor,
                                                              int* __restrict__ bucket,
                                                              int M, int E) {
    __shared__ union {
        struct { short As[2][64 * 32]; short Bs[2][256 * 32]; } k;  // 8KB + 32KB = 40KB
        short Cs[32 * 260];                                         // 16.6KB (epilogue)
    } u;

    const int bid = blockIdx.x;
    const int tid = threadIdx.x;

    if (bid < SBLK) {
        // ---------------- scatter role (VERIFIED logic, grid-stride) -------
        const int stride = SBLK * 256;
        for (int i = bid * 256 + tid; i < E; i += stride) {
            const int r = erow[i];
            const int c = ecol[i];
            const int pos = atomicAdd(&cursor[r], 1);
            if (pos < BCAP) bucket[((size_t)r << 6) + pos] = c;
        }
        return;
    }

    // ---------------- gemm role (byte-identical VERIFIED R2 body) ----------
    const int w    = tid >> 6;
    const int lane = tid & 63;
    const int rowbase = (bid - SBLK) * 64;

    const int wm = w & 1;     // 32-row half
    const int wn = w >> 1;    // 128-col half
    const int srow = lane >> 2;
    const int skq  = (lane & 3) << 3;
    const int fm = lane & 15;
    const int fq = lane >> 4;

    floatx4 acc[2][8];
#pragma unroll
    for (int i = 0; i < 2; ++i)
#pragma unroll
        for (int j = 0; j < 8; ++j)
            acc[i][j] = (floatx4){0.f, 0.f, 0.f, 0.f};

    // A-staging: wave w owns 16 rows (w*16+srow), 2 float4 per lane per K-step.
    const int arow = min(rowbase + w * 16 + srow, M - 1);
    const size_t abase = (size_t)arow * NFEAT + skq;
    const int lrowA = (w * 16 + srow) * 32 + skq;     // LDS halfword offset within As[buf]

    // B-staging: wave w stages segs 4w..4w+3 (16 n-rows each, 16B/lane).
#define STAGE_B(buf, k0)                                                                      \
    {                                                                                         \
        _Pragma("unroll")                                                                     \
        for (int t = 0; t < 4; ++t) {                                                         \
            const int seg = w * 4 + t;                                                        \
            const int nr  = seg * 16 + srow;                                                  \
            __builtin_amdgcn_global_load_lds(                                                 \
                (const __attribute__((address_space(1))) void*)(Wt + (size_t)nr * NFEAT + (k0) + skq), \
                (__attribute__((address_space(3))) void*)(&u.k.Bs[buf][seg * 512]), 16, 0, 0); \
        }                                                                                     \
    }

    // ---- prologue: fill buffer 0 with k0=0 ----
    STAGE_B(0, 0)
    {
        const float4* xp = (const float4*)&x[abase];
        const float4 u0 = xp[0];
        const float4 u1 = xp[1];
        uint4 o;
        o.x = pack_bf16_rh(u0.x, u0.y);
        o.y = pack_bf16_rh(u0.z, u0.w);
        o.z = pack_bf16_rh(u1.x, u1.y);
        o.w = pack_bf16_rh(u1.z, u1.w);
        *(uint4*)&u.k.As[0][lrowA] = o;
    }
    __syncthreads();

    int cur = 0;
    for (int k0 = 0; k0 < NFEAT; k0 += 32) {
        const int nxt = cur ^ 1;
        const bool have_next = (k0 + 32) < NFEAT;
        float4 p0, p1;
        if (have_next) {
            // Issue next tile's loads FIRST so latency hides under MFMA.
            const float4* xp = (const float4*)&x[abase + k0 + 32];
            p0 = xp[0];
            p1 = xp[1];
            STAGE_B(nxt, k0 + 32)
        }

        short8 af[2];
#pragma unroll
        for (int mt = 0; mt < 2; ++mt)
            af[mt] = *(const short8*)&u.k.As[cur][(wm * 32 + mt * 16 + fm) * 32 + fq * 8];
#pragma unroll
        for (int nt = 0; nt < 8; ++nt) {
            const short8 bfr = *(const short8*)&u.k.Bs[cur][(wn * 128 + nt * 16 + fm) * 32 + fq * 8];
            acc[0][nt] = __builtin_amdgcn_mfma_f32_16x16x32_bf16(af[0], bfr, acc[0][nt], 0, 0, 0);
            acc[1][nt] = __builtin_amdgcn_mfma_f32_16x16x32_bf16(af[1], bfr, acc[1][nt], 0, 0, 0);
        }

        if (have_next) {
            uint4 o;
            o.x = pack_bf16_rh(p0.x, p0.y);
            o.y = pack_bf16_rh(p0.z, p0.w);
            o.z = pack_bf16_rh(p1.x, p1.y);
            o.w = pack_bf16_rh(p1.z, p1.w);
            *(uint4*)&u.k.As[nxt][lrowA] = o;
        }
        __syncthreads();   // drains vmcnt (B lds) + lgkmcnt (A write) for nxt
        cur = nxt;
    }

    // Epilogue: 2 passes of 32 rows through Cs (stride 260).
#pragma unroll
    for (int p = 0; p < 2; ++p) {
        __syncthreads();
        if (wm == p) {
#pragma unroll
            for (int mt = 0; mt < 2; ++mt)
#pragma unroll
                for (int nt = 0; nt < 8; ++nt)
#pragma unroll
                    for (int r = 0; r < 4; ++r)
                        u.Cs[(mt * 16 + fq * 4 + r) * 260 + wn * 128 + nt * 16 + fm] =
                            (short)f2bf(acc[mt][nt][r]);
        }
        __syncthreads();
        // 32 rows x 256 cols: one wave handles one row/iter
#pragma unroll
        for (int kk = 0; kk < 8; ++kk) {
            const int idx = tid + kk * 256;
            const int lrow = idx >> 6;
            const int c4 = (idx & 63) << 2;
            const int grow = rowbase + p * 32 + lrow;
            const uint2 vv = *(const uint2*)&u.Cs[lrow * 260 + c4];
            const float f0 = bf2f_lo(vv.x), f1 = bf2f_hi(vv.x);
            const float f2 = bf2f_lo(vv.y), f3 = bf2f_hi(vv.y);
            const float4 A1 = *(const float4*)&a[c4];
            const float4 A2 = *(const float4*)&a[NCLASS + c4];
            float p1 = f0 * A1.x + f1 * A1.y + f2 * A1.z + f3 * A1.w;
            float p2 = f0 * A2.x + f1 * A2.y + f2 * A2.z + f3 * A2.w;
#pragma unroll
            for (int off = 1; off < 64; off <<= 1) {
                p1 += __shfl_xor(p1, off);
                p2 += __shfl_xor(p2, off);
            }
            if (grow < M) {
                *(uint2*)&hb[(size_t)grow * NCLASS + c4] = vv;
                if (lane == 0) {
                    s_row[grow] = p1;
                    s_col[grow] = p2;
                }
            }
        }
    }
}

// ---------------------------------------------------------------------------
// Aggregation + elu + log_softmax (VERIFIED). One wave per row; lane holds
// 4 features. e = exp(-lrelu(s_row[r] + s_col[c])) inline.
// ---------------------------------------------------------------------------
__global__ __launch_bounds__(256) void aggregate_kernel(const unsigned short* __restrict__ hb,
                                                        const int* __restrict__ bucket,
                                                        const int* __restrict__ cnt,
                                                        const float* __restrict__ s_row,
                                                        const float* __restrict__ s_col,
                                                        float* __restrict__ out, int n) {
    const int wave = (int)((blockIdx.x * (size_t)blockDim.x + threadIdx.x) >> 6);
    const int lane = threadIdx.x & 63;
    if (wave >= n) return;
    const int r = wave;
    const int jb = r << 6;
    const int je = jb + min(cnt[r], BCAP);
    const int fo = lane << 2;
    const float sr = s_row[r];

    float rowsum = 0.f;
    int j = jb;

#define EDGE_E(c) ({ const float _l = sr + s_col[c];                         \
                     const float _lr = _l > 0.f ? _l : NEG_SLOPE * _l;       \
                     __expf(-_lr); })

#ifdef HAVE_DOT2
    float ac0 = 0.f, ac1 = 0.f, ac2 = 0.f, ac3 = 0.f;
    for (; j + 3 < je; j += 4) {
        const int4 cv = *(const int4*)&bucket[j];
        const uint2 g0 = *(const uint2*)&hb[(size_t)cv.x * NCLASS + fo];
        const uint2 g1 = *(const uint2*)&hb[(size_t)cv.y * NCLASS + fo];
        const uint2 g2 = *(const uint2*)&hb[(size_t)cv.z * NCLASS + fo];
        const uint2 g3 = *(const uint2*)&hb[(size_t)cv.w * NCLASS + fo];
        const float e0 = EDGE_E(cv.x);
        const float e1 = EDGE_E(cv.y);
        const float e2 = EDGE_E(cv.z);
        const float e3 = EDGE_E(cv.w);
        const unsigned ep01 = pack_bf16_rh(e0, e1);
        const unsigned ep23 = pack_bf16_rh(e2, e3);
        rowsum += (e0 + e1) + (e2 + e3);
        ac0 = dot2bf(__builtin_amdgcn_perm(g1.x, g0.x, 0x05040100), ep01, ac0);
        ac1 = dot2bf(__builtin_amdgcn_perm(g1.x, g0.x, 0x07060302), ep01, ac1);
        ac2 = dot2bf(__builtin_amdgcn_perm(g1.y, g0.y, 0x05040100), ep01, ac2);
        ac3 = dot2bf(__builtin_amdgcn_perm(g1.y, g0.y, 0x07060302), ep01, ac3);
        ac0 = dot2bf(__builtin_amdgcn_perm(g3.x, g2.x, 0x05040100), ep23, ac0);
        ac1 = dot2bf(__builtin_amdgcn_perm(g3.x, g2.x, 0x07060302), ep23, ac1);
        ac2 = dot2bf(__builtin_amdgcn_perm(g3.y, g2.y, 0x05040100), ep23, ac2);
        ac3 = dot2bf(__builtin_amdgcn_perm(g3.y, g2.y, 0x07060302), ep23, ac3);
    }
    float4 acc = make_float4(ac0, ac1, ac2, ac3);
#else
    float4 acc = make_float4(0.f, 0.f, 0.f, 0.f);
    for (; j + 3 < je; j += 4) {
        const int4 cv = *(const int4*)&bucket[j];
        const uint2 g0 = *(const uint2*)&hb[(size_t)cv.x * NCLASS + fo];
        const uint2 g1 = *(const uint2*)&hb[(size_t)cv.y * NCLASS + fo];
        const uint2 g2 = *(const uint2*)&hb[(size_t)cv.z * NCLASS + fo];
        const uint2 g3 = *(const uint2*)&hb[(size_t)cv.w * NCLASS + fo];
        const float e0 = EDGE_E(cv.x);
        const float e1 = EDGE_E(cv.y);
        const float e2 = EDGE_E(cv.z);
        const float e3 = EDGE_E(cv.w);
        rowsum += (e0 + e1) + (e2 + e3);
        acc.x += e0 * bf2f_lo(g0.x) + e1 * bf2f_lo(g1.x) + e2 * bf2f_lo(g2.x) + e3 * bf2f_lo(g3.x);
        acc.y += e0 * bf2f_hi(g0.x) + e1 * bf2f_hi(g1.x) + e2 * bf2f_hi(g2.x) + e3 * bf2f_hi(g3.x);
        acc.z += e0 * bf2f_lo(g0.y) + e1 * bf2f_lo(g1.y) + e2 * bf2f_lo(g2.y) + e3 * bf2f_lo(g3.y);
        acc.w += e0 * bf2f_hi(g0.y) + e1 * bf2f_hi(g1.y) + e2 * bf2f_hi(g2.y) + e3 * bf2f_hi(g3.y);
    }
#endif
    for (; j < je; ++j) {
        const int c = bucket[j];
        const uint2 g = *(const uint2*)&hb[(size_t)c * NCLASS + fo];
        const float e = EDGE_E(c);
        rowsum += e;
        acc.x += e * bf2f_lo(g.x);
        acc.y += e * bf2f_hi(g.x);
        acc.z += e * bf2f_lo(g.y);
        acc.w += e * bf2f_hi(g.y);
    }

    const float inv = 1.f / rowsum;
    float v[4] = {acc.x * inv, acc.y * inv, acc.z * inv, acc.w * inv};
#pragma unroll
    for (int i = 0; i < 4; ++i)
        v[i] = v[i] > 0.f ? v[i] : __expf(v[i]) - 1.f;

    float m = fmaxf(fmaxf(v[0], v[1]), fmaxf(v[2], v[3]));
#pragma unroll
    for (int off = 32; off > 0; off >>= 1) m = fmaxf(m, __shfl_xor(m, off));
    float s = 0.f;
#pragma unroll
    for (int i = 0; i < 4; ++i) s += __expf(v[i] - m);
#pragma unroll
    for (int off = 32; off > 0; off >>= 1) s += __shfl_xor(s, off);
    const float lse = m + __logf(s);

    float4 o = make_float4(v[0] - lse, v[1] - lse, v[2] - lse, v[3] - lse);
    *(float4*)&out[(size_t)r * NCLASS + fo] = o;
}

// ---------------------------------------------------------------------------
extern "C" void kernel_launch(void* const* d_in, const int* in_sizes, int n_in,
                              void* d_out, int out_size, void* d_ws, size_t ws_size,
                              hipStream_t stream) {
    const float* x  = (const float*)d_in[0];
    const float* W  = (const float*)d_in[1];
    const float* a  = (const float*)d_in[2];
    const int* edge = (const int*)d_in[3];
    float* out = (float*)d_out;

    const int M = in_sizes[0] / NFEAT;         // 50000
    const int E = in_sizes[3] / 2;             // 850000
    const int* row = edge;
    const int* col = edge + E;

    char* ws = (char*)d_ws;
    size_t off = 0;
    auto carve = [&](size_t bytes) -> char* {
        char* p = ws + off;
        off = (off + bytes + 255) & ~(size_t)255;
        return p;
    };
    unsigned short* Wt = (unsigned short*)carve((size_t)NCLASS * NFEAT * sizeof(short));
    unsigned short* hb = (unsigned short*)carve((size_t)M * NCLASS * sizeof(short)); // 25.6MB
    int*   cursor   = (int*)carve((size_t)M * sizeof(int));
    float* s_row    = (float*)carve((size_t)M * sizeof(float));
    float* s_col    = (float*)carve((size_t)M * sizeof(float));
    int*   bucket   = (int*)carve((size_t)M * BCAP * sizeof(int));   // 12.8MB

    init_kernel<<<512, 256, 0, stream>>>(W, Wt, cursor, M);

    gemm_scatter_kernel<<<SBLK + GBLK, 256, 0, stream>>>(x, Wt, hb, a, s_row, s_col,
                                                         row, col, cursor, bucket, M, E);

    aggregate_kernel<<<(M + 3) / 4, 256, 0, stream>>>(hb, bucket, cursor, s_row, s_col, out, M);
}